// Round 8
// baseline (428.363 us; speedup 1.0000x reference)
//
#include <hip/hip_runtime.h>
#include <hip/hip_bf16.h>

#define BB 64
#define DD 1024
#define HH 16
#define LL 4101          // 1 + 4 + 4096
#define NCH 4
#define CHUNK 1026       // ceil(4101/4)
#define SCALE 0.125f
#define LN_EPS 1e-5f
#define XROWF 1028       // fp32 row stride in LDS (4112 B): rows advance 4 banks
#define BUFF  (16 * XROWF)

typedef float  f32x4 __attribute__((ext_vector_type(4)));
typedef short  s16x8 __attribute__((ext_vector_type(8)));
typedef unsigned int u32x4 __attribute__((ext_vector_type(4)));

// workspace layout (float offsets)
#define WS_QVEC 0               // 1024
#define WS_GU   1024            // 16384
#define WS_G    17408           // 16  (Gv)
#define WS_CB   17424           // 16
#define WS_GP   17440           // 64  (G partials per h,q)
#define WS_BP   17504           // 64
#define WS_PL   17568           // 256*16 = 4096
#define WS_PM   21664           // 4096
#define WS_PA   25760           // 256*16*1024 = 4194304
#define WS_CTX  4220064         // 65536
#define WS_POOL 4285600         // 65536

__device__ __forceinline__ unsigned int pk2(float a, float b) {
    __hip_bfloat162 h = __float22bfloat162_rn(make_float2(a, b));
    unsigned int r;
    __builtin_memcpy(&r, &h, 4);
    return r;
}

__device__ __forceinline__ const float* rowptr(int gr, int b, const float* cls,
                                               const float* sto, const float* pat) {
    if (gr == 0) return cls + (size_t)b * DD;
    if (gr <= 4) return sto + ((size_t)b * 4 + (gr - 1)) * DD;
    return pat + ((size_t)b * 4096 + (gr - 5)) * DD;
}

// ---------------- prep: qp = Wq*query + bq ----------------
__global__ void k_qvec(const float* __restrict__ query, const float* __restrict__ Wq,
                       const float* __restrict__ bq, float* __restrict__ qvec) {
    int j = blockIdx.x; int lane = threadIdx.x;          // 64 threads
    const float4* wr = reinterpret_cast<const float4*>(Wq + (size_t)j * DD);
    const float4* qr = reinterpret_cast<const float4*>(query);
    float s = 0.f;
#pragma unroll
    for (int k = 0; k < 4; ++k) {
        float4 a = wr[k * 64 + lane];
        float4 q = qr[k * 64 + lane];
        s += a.x * q.x + a.y * q.y + a.z * q.z + a.w * q.w;
    }
#pragma unroll
    for (int m = 1; m < 64; m <<= 1) s += __shfl_xor(s, m, 64);
    if (lane == 0) qvec[j] = s + bq[j];
}

// ---------------- prep: gu = g .* (scale*Wk_h^T qp_h); per-(h,q) partial G, Bu ----------------
__global__ void k_u(const float* __restrict__ Wk, const float* __restrict__ qvec,
                    const float* __restrict__ g, const float* __restrict__ bln,
                    float* __restrict__ gu, float* __restrict__ Gp, float* __restrict__ Bp) {
    int h = blockIdx.x >> 2, q = blockIdx.x & 3;        // 64 blocks, 256 threads
    int tid = threadIdx.x;
    int w = tid >> 6, lane = tid & 63;
    __shared__ float qs[64];
    __shared__ float red[8];
    if (tid < 64) qs[tid] = qvec[h * 64 + tid];
    __syncthreads();
    int d = q * 256 + tid;
    float a = 0.f;
#pragma unroll 8
    for (int i = 0; i < 64; ++i) a += qs[i] * Wk[(size_t)(h * 64 + i) * DD + d];
    float u = a * SCALE;
    float guv = u * g[d];
    gu[(size_t)h * DD + d] = guv;
    float Gv_ = guv, Bv_ = u * bln[d];
#pragma unroll
    for (int m = 1; m < 64; m <<= 1) { Gv_ += __shfl_xor(Gv_, m, 64); Bv_ += __shfl_xor(Bv_, m, 64); }
    if (lane == 0) { red[2 * w] = Gv_; red[2 * w + 1] = Bv_; }
    __syncthreads();
    if (tid == 0) {
        Gp[h * 4 + q] = red[0] + red[2] + red[4] + red[6];
        Bp[h * 4 + q] = red[1] + red[3] + red[5] + red[7];
    }
}

// ---------------- prep: Gv, CB ----------------
__global__ void k_cq(const float* __restrict__ qvec, const float* __restrict__ bk,
                     const float* __restrict__ Gp, const float* __restrict__ Bp,
                     float* __restrict__ Gv, float* __restrict__ CB) {
    int h = threadIdx.x;
    if (h < HH) {
        float G = Gp[h * 4] + Gp[h * 4 + 1] + Gp[h * 4 + 2] + Gp[h * 4 + 3];
        float Bu = Bp[h * 4] + Bp[h * 4 + 1] + Bp[h * 4 + 2] + Bp[h * 4 + 3];
        float s = 0.f;
        for (int i = 0; i < 64; ++i) s += qvec[h * 64 + i] * bk[h * 64 + i];
        Gv[h] = G;
        CB[h] = Bu + s * SCALE;
    }
}

// ---------------- fused main: async global_load_lds dbuf, MFMA stats ----------------
// 256 blocks x 512 threads (8 waves, 1 block/CU). 16-row fp32 tiles.
__global__ __launch_bounds__(512, 1) void k_main(
    const float* __restrict__ cls, const float* __restrict__ sto,
    const float* __restrict__ pat, const float* __restrict__ gu,
    const float* __restrict__ Gv, const float* __restrict__ CBv,
    float* __restrict__ pA, float* __restrict__ pl, float* __restrict__ pM) {

    __shared__ __align__(16) float Xf[2 * BUFF];        // 131,584 B fp32 dbuf
    __shared__ __align__(16) f32x4 csr[8][64];          // 8 KB score partials
    __shared__ float sstat[2][16][8];                   // [stat][row][wave]
    __shared__ float2 mrs[16];
    __shared__ __align__(8) ushort alds[16 * 32];       // rows 16..31 stay zero

    const int blk = blockIdx.x;
    const int b = blk >> 2, ch = blk & 3;
    const int row0 = ch * CHUNK;
    const int rows = min(CHUNK, LL - row0);
    const int nt = (rows + 15) >> 4;
    const int tid = threadIdx.x;
    const int w = tid >> 6, lane = tid & 63;
    const int lm = lane & 15, lg = lane >> 4;

    // zero-init LDS (alds rows 16-31 must be zero; Xf guards NaN on first tiles)
    for (int i = tid; i < 2 * BUFF; i += 512) Xf[i] = 0.f;
    if (tid < 256) reinterpret_cast<unsigned int*>(alds)[tid] = 0u;

    // op2 gu B-fragments: head=lm, d = w*128 + s*32 + lg*8 + j
    s16x8 guf[4];
    {
        const float* gubase = gu + (size_t)lm * DD + w * 128 + lg * 8;
#pragma unroll
        for (int s = 0; s < 4; ++s) {
            const float* p = gubase + s * 32;
            u32x4 t;
#pragma unroll
            for (int j = 0; j < 4; ++j) t[j] = pk2(p[2 * j], p[2 * j + 1]);
            s16x8 f; __builtin_memcpy(&f, &t, 16);
            guf[s] = f;
        }
    }
    s16x8 ones;
#pragma unroll
    for (int j = 0; j < 8; ++j) ones[j] = (short)0x3F80;
    const float Gh = Gv[lm], CBh = CBv[lm];

    f32x4 acc[8];
#pragma unroll
    for (int i = 0; i < 8; ++i) acc[i] = (f32x4){0.f, 0.f, 0.f, 0.f};
    float lacc = 0.f, macc = 0.f;

#define ISSUE_TILE(T)                                                              \
    {                                                                              \
        int buf_ = (T) & 1;                                                        \
        _Pragma("unroll")                                                          \
        for (int rr = 0; rr < 2; ++rr) {                                           \
            int rl = 2 * w + rr;                                                   \
            int rloc = (T) * 16 + rl;                                              \
            if (rloc < rows) {                                                     \
                const float* rp = rowptr(row0 + rloc, b, cls, sto, pat);           \
                _Pragma("unroll")                                                  \
                for (int c = 0; c < 4; ++c) {                                      \
                    __builtin_amdgcn_global_load_lds(                              \
                        (const __attribute__((address_space(1))) unsigned int*)    \
                            (rp + c * 256 + lane * 4),                             \
                        (__attribute__((address_space(3))) unsigned int*)          \
                            (&Xf[buf_ * BUFF + rl * XROWF + c * 256]),             \
                        16, 0, 0);                                                 \
                }                                                                  \
            }                                                                      \
        }                                                                          \
    }

    __syncthreads();          // zero-init visible
    ISSUE_TILE(0);
    __syncthreads();          // tile 0 landed (vmcnt+lgkm drain + barrier)

    for (int t = 0; t < nt; ++t) {
        const int buf = t & 1;
        if (t + 1 < nt) ISSUE_TILE(t + 1);

        // ---- op2: scores + stats via MFMA (fp32 LDS -> bf16 frags) ----
        {
            f32x4 c0 = {0.f,0.f,0.f,0.f}, q0 = {0.f,0.f,0.f,0.f}, m0 = {0.f,0.f,0.f,0.f};
            const float* Ab = &Xf[buf * BUFF + lm * XROWF + w * 128 + lg * 8];
#pragma unroll
            for (int s = 0; s < 4; ++s) {
                float4 x0 = *reinterpret_cast<const float4*>(Ab + s * 32);
                float4 x1 = *reinterpret_cast<const float4*>(Ab + s * 32 + 4);
                u32x4 tt;
                tt[0] = pk2(x0.x, x0.y); tt[1] = pk2(x0.z, x0.w);
                tt[2] = pk2(x1.x, x1.y); tt[3] = pk2(x1.z, x1.w);
                s16x8 a0; __builtin_memcpy(&a0, &tt, 16);
                c0 = __builtin_amdgcn_mfma_f32_16x16x32_bf16(a0, guf[s], c0, 0, 0, 0);
                q0 = __builtin_amdgcn_mfma_f32_16x16x32_bf16(a0, a0,     q0, 0, 0, 0);
                m0 = __builtin_amdgcn_mfma_f32_16x16x32_bf16(a0, ones,   m0, 0, 0, 0);
            }
            csr[w][lane] = c0;
            if (lg == (lm >> 2)) sstat[0][lm][w] = q0[lm & 3];
            if (lm == 0) {
#pragma unroll
                for (int i = 0; i < 4; ++i) sstat[1][lg * 4 + i][w] = m0[i];
            }
        }
        asm volatile("s_waitcnt lgkmcnt(0)" ::: "memory");
        __builtin_amdgcn_s_barrier();                       // csr/sstat visible

        // ---- finalize (redundant per wave) ----
        if (lane < 16) {
            const float4* q4 = reinterpret_cast<const float4*>(&sstat[0][lane][0]);
            float4 qa = q4[0], qb = q4[1];
            const float4* m4 = reinterpret_cast<const float4*>(&sstat[1][lane][0]);
            float4 ma = m4[0], mb = m4[1];
            float s2 = qa.x + qa.y + qa.z + qa.w + qb.x + qb.y + qb.z + qb.w;
            float s1 = ma.x + ma.y + ma.z + ma.w + mb.x + mb.y + mb.z + mb.w;
            float mean = s1 * (1.f / 1024.f);
            float var  = s2 * (1.f / 1024.f) - mean * mean;
            float rstd = rsqrtf(var + LN_EPS);
            mrs[lane] = make_float2(rstd, -mean * rstd);
        }
        asm volatile("s_waitcnt lgkmcnt(0)" ::: "memory");
        __builtin_amdgcn_sched_barrier(0);
        {
            f32x4 dv = csr[0][lane];
#pragma unroll
            for (int wp = 1; wp < 8; ++wp) dv += csr[wp][lane];
            int rbase = lg * 4;
            float al[4];
#pragma unroll
            for (int i = 0; i < 4; ++i) {
                float2 mr = mrs[rbase + i];
                float sc = dv[i] * mr.x + (mr.y * Gh + CBh);
                bool vld = (t * 16 + rbase + i) < rows;
                float p = vld ? __expf(sc) : 0.f;
                lacc += p;
                macc += p * mr.y;
                al[i] = p * mr.x;
            }
            *reinterpret_cast<unsigned int*>(&alds[lm * 32 + rbase])     = pk2(al[0], al[1]);
            *reinterpret_cast<unsigned int*>(&alds[lm * 32 + rbase + 2]) = pk2(al[2], al[3]);
        }
        asm volatile("s_waitcnt lgkmcnt(0)" ::: "memory");
        __builtin_amdgcn_sched_barrier(0);

        // ---- op4: acc[h][d] += alpha^T . X  (k 0..15 real, 16..31 zero) ----
        {
            s16x8 af = *reinterpret_cast<const s16x8*>(&alds[lm * 32 + lg * 8]);
            const float* Bb = &Xf[buf * BUFF + (lg & 1) * 8 * XROWF + w * 128 + lm];
            bool act = lg < 2;
#pragma unroll
            for (int dt = 0; dt < 8; ++dt) {
                float bx[8];
#pragma unroll
                for (int j = 0; j < 8; ++j) bx[j] = act ? Bb[j * XROWF + dt * 16] : 0.f;
                u32x4 tb;
                tb[0] = pk2(bx[0], bx[1]); tb[1] = pk2(bx[2], bx[3]);
                tb[2] = pk2(bx[4], bx[5]); tb[3] = pk2(bx[6], bx[7]);
                s16x8 bf; __builtin_memcpy(&bf, &tb, 16);
                acc[dt] = __builtin_amdgcn_mfma_f32_16x16x32_bf16(af, bf, acc[dt], 0, 0, 0);
            }
        }
        asm volatile("s_waitcnt vmcnt(0)" ::: "memory");    // t+1 loads landed
        asm volatile("s_waitcnt lgkmcnt(0)" ::: "memory");
        __builtin_amdgcn_s_barrier();                       // buffers rotate
    }

    // write partial A  (pA[blk][h][1024])
    size_t pabase = ((size_t)blk << 14);
#pragma unroll
    for (int dt = 0; dt < 8; ++dt) {
#pragma unroll
        for (int i = 0; i < 4; ++i) {
            int h = lg * 4 + i;
            pA[pabase + ((size_t)h << 10) + w * 128 + dt * 16 + lm] = acc[dt][i];
        }
    }
    if (w == 0) {
        lacc += __shfl_xor(lacc, 16, 64); lacc += __shfl_xor(lacc, 32, 64);
        macc += __shfl_xor(macc, 16, 64); macc += __shfl_xor(macc, 32, 64);
        if (lane < 16) {
            pl[blk * 16 + lane] = lacc;
            pM[blk * 16 + lane] = -macc;
        }
    }
#undef ISSUE_TILE
}

// ---------------- combine partials: sbar = (g.*(A - M))/l + b  (overlays pA ch=0) ----------------
__global__ void k_comb(float* __restrict__ pA, const float* __restrict__ pl,
                       const float* __restrict__ pM, const float* __restrict__ g,
                       const float* __restrict__ bln) {
    int blk = blockIdx.x; int b = blk >> 4; int h = blk & 15; int tid = threadIdx.x;
    float l = 0.f, M = 0.f;
#pragma unroll
    for (int ch = 0; ch < NCH; ++ch) {
        l += pl[(b * NCH + ch) * 16 + h];
        M += pM[(b * NCH + ch) * 16 + h];
    }
    float inv = 1.f / l;
    float4 s = make_float4(0.f, 0.f, 0.f, 0.f);
#pragma unroll
    for (int ch = 0; ch < NCH; ++ch) {
        const float4* p4 = reinterpret_cast<const float4*>(
            pA + (((size_t)(b * NCH + ch) * 16 + h) << 10));
        float4 v = p4[tid];
        s.x += v.x; s.y += v.y; s.z += v.z; s.w += v.w;
    }
    float4 g4 = *reinterpret_cast<const float4*>(&g[tid * 4]);
    float4 b4 = *reinterpret_cast<const float4*>(&bln[tid * 4]);
    float4 o;
    o.x = g4.x * (s.x - M) * inv + b4.x;
    o.y = g4.y * (s.y - M) * inv + b4.y;
    o.z = g4.z * (s.z - M) * inv + b4.z;
    o.w = g4.w * (s.w - M) * inv + b4.w;
    float4* dst = reinterpret_cast<float4*>(pA + (((size_t)(b * NCH) * 16 + h) << 10));
    dst[tid] = o;
}

// ---------------- ctx = Wv_h * sbar_h + bv ----------------
__global__ void k_ctx(const float* __restrict__ Wv, const float* __restrict__ bv,
                      const float* __restrict__ pA, float* __restrict__ ctx) {
    int j = blockIdx.x; int h = j >> 6;
    int w = threadIdx.x >> 6, lane = threadIdx.x & 63;
    const float4* wr = reinterpret_cast<const float4*>(Wv + (size_t)j * DD);
    float4 wv[4];
#pragma unroll
    for (int k = 0; k < 4; ++k) wv[k] = wr[k * 64 + lane];
    float bvj = bv[j];
    for (int bb2 = w * 16; bb2 < w * 16 + 16; ++bb2) {
        const float4* sr = reinterpret_cast<const float4*>(
            pA + (((size_t)(bb2 * NCH) * 16 + h) << 10));
        float s = 0.f;
#pragma unroll
        for (int k = 0; k < 4; ++k) {
            float4 v = sr[k * 64 + lane];
            s += wv[k].x * v.x + wv[k].y * v.y + wv[k].z * v.z + wv[k].w * v.w;
        }
#pragma unroll
        for (int m = 1; m < 64; m <<= 1) s += __shfl_xor(s, m, 64);
        if (lane == 0) ctx[(size_t)bb2 * DD + j] = s + bvj;
    }
}

// ---------------- pooled = Wo * ctx + bo ----------------
__global__ void k_pool(const float* __restrict__ Wo, const float* __restrict__ bo,
                       const float* __restrict__ ctx, float* __restrict__ pooled) {
    int j = blockIdx.x;
    int w = threadIdx.x >> 6, lane = threadIdx.x & 63;
    const float4* wr = reinterpret_cast<const float4*>(Wo + (size_t)j * DD);
    float4 wv[4];
#pragma unroll
    for (int k = 0; k < 4; ++k) wv[k] = wr[k * 64 + lane];
    float boj = bo[j];
    for (int bb2 = w * 16; bb2 < w * 16 + 16; ++bb2) {
        const float4* cr4 = reinterpret_cast<const float4*>(ctx + (size_t)bb2 * DD);
        float s = 0.f;
#pragma unroll
        for (int k = 0; k < 4; ++k) {
            float4 v = cr4[k * 64 + lane];
            s += wv[k].x * v.x + wv[k].y * v.y + wv[k].z * v.z + wv[k].w * v.w;
        }
#pragma unroll
        for (int m = 1; m < 64; m <<= 1) s += __shfl_xor(s, m, 64);
        if (lane == 0) pooled[(size_t)bb2 * DD + j] = s + boj;
    }
}

// ---------------- final LN + classifier head ----------------
__global__ void k_head(const float* __restrict__ pooled, const float* __restrict__ g2,
                       const float* __restrict__ b2, const float* __restrict__ Wp,
                       const float* __restrict__ bp, float* __restrict__ out) {
    int b = blockIdx.x; int tid = threadIdx.x;
    __shared__ float pln[DD];
    __shared__ float red[8];
    const float4* pr = reinterpret_cast<const float4*>(pooled + (size_t)b * DD);
    float4 v = pr[tid];
    float s1 = v.x + v.y + v.z + v.w;
    float s2 = v.x * v.x + v.y * v.y + v.z * v.z + v.w * v.w;
#pragma unroll
    for (int m = 1; m < 64; m <<= 1) { s1 += __shfl_xor(s1, m, 64); s2 += __shfl_xor(s2, m, 64); }
    int w = tid >> 6, lane = tid & 63;
    if (lane == 0) { red[2 * w] = s1; red[2 * w + 1] = s2; }
    __syncthreads();
    s1 = red[0] + red[2] + red[4] + red[6];
    s2 = red[1] + red[3] + red[5] + red[7];
    float mean = s1 * (1.f / 1024.f);
    float var  = s2 * (1.f / 1024.f) - mean * mean;
    float rstd = rsqrtf(var + LN_EPS);
    int d0 = tid * 4;
    pln[d0 + 0] = (v.x - mean) * rstd * g2[d0 + 0] + b2[d0 + 0];
    pln[d0 + 1] = (v.y - mean) * rstd * g2[d0 + 1] + b2[d0 + 1];
    pln[d0 + 2] = (v.z - mean) * rstd * g2[d0 + 2] + b2[d0 + 2];
    pln[d0 + 3] = (v.w - mean) * rstd * g2[d0 + 3] + b2[d0 + 3];
    __syncthreads();
    int q = tid & 15, c = tid >> 4;
    if (c < 14) {
        float s = 0.f;
#pragma unroll 8
        for (int i = 0; i < 64; ++i) {
            int d = i * 16 + q;
            s += pln[d] * Wp[c * DD + d];
        }
#pragma unroll
        for (int m = 1; m < 16; m <<= 1) s += __shfl_xor(s, m, 64);
        if (q == 0) out[b * 14 + c] = s + bp[c];
    }
}

extern "C" void kernel_launch(void* const* d_in, const int* in_sizes, int n_in,
                              void* d_out, int out_size, void* d_ws, size_t ws_size,
                              hipStream_t stream) {
    const float* cls   = (const float*)d_in[0];
    const float* sto   = (const float*)d_in[1];
    const float* pat   = (const float*)d_in[2];
    const float* query = (const float*)d_in[3];
    const float* g     = (const float*)d_in[4];
    const float* bln   = (const float*)d_in[5];
    const float* Wq    = (const float*)d_in[6];
    const float* Wk    = (const float*)d_in[7];
    const float* Wv    = (const float*)d_in[8];
    const float* bq    = (const float*)d_in[9];
    const float* bk    = (const float*)d_in[10];
    const float* bv    = (const float*)d_in[11];
    const float* Wo    = (const float*)d_in[12];
    const float* bo    = (const float*)d_in[13];
    const float* g2    = (const float*)d_in[14];
    const float* b2    = (const float*)d_in[15];
    const float* Wp    = (const float*)d_in[16];
    const float* bp    = (const float*)d_in[17];

    float* ws     = (float*)d_ws;
    float* qvec   = ws + WS_QVEC;
    float* gu     = ws + WS_GU;
    float* Gv     = ws + WS_G;
    float* CB     = ws + WS_CB;
    float* Gp     = ws + WS_GP;
    float* Bp     = ws + WS_BP;
    float* pl     = ws + WS_PL;
    float* pM     = ws + WS_PM;
    float* pA     = ws + WS_PA;
    float* ctx    = ws + WS_CTX;
    float* pooled = ws + WS_POOL;
    float* out    = (float*)d_out;

    hipLaunchKernelGGL(k_qvec, dim3(1024), dim3(64), 0, stream, query, Wq, bq, qvec);
    hipLaunchKernelGGL(k_u,    dim3(64),   dim3(256), 0, stream, Wk, qvec, g, bln, gu, Gp, Bp);
    hipLaunchKernelGGL(k_cq,   dim3(1),    dim3(64), 0, stream, qvec, bk, Gp, Bp, Gv, CB);
    hipLaunchKernelGGL(k_main, dim3(BB * NCH), dim3(512), 0, stream,
                       cls, sto, pat, gu, Gv, CB, pA, pl, pM);
    hipLaunchKernelGGL(k_comb, dim3(BB * HH), dim3(256), 0, stream, pA, pl, pM, g, bln);
    hipLaunchKernelGGL(k_ctx,  dim3(1024), dim3(256), 0, stream, Wv, bv, pA, ctx);
    hipLaunchKernelGGL(k_pool, dim3(1024), dim3(256), 0, stream, Wo, bo, ctx, pooled);
    hipLaunchKernelGGL(k_head, dim3(64),   dim3(256), 0, stream, pooled, g2, b2, Wp, bp, out);
}

// Round 9
// 373.710 us; speedup vs baseline: 1.1462x; 1.1462x over previous
//
#include <hip/hip_runtime.h>
#include <hip/hip_bf16.h>

#define BB 64
#define DD 1024
#define HH 16
#define LL 4101          // 1 + 4 + 4096
#define NCH 4
#define CHUNK 1026       // ceil(4101/4)
#define SCALE 0.125f
#define LN_EPS 1e-5f
#define XROWF 1028       // fp32 row stride in LDS (4112 B)
#define BUFF  (16 * XROWF)

typedef float  f32x4 __attribute__((ext_vector_type(4)));
typedef short  s16x8 __attribute__((ext_vector_type(8)));
typedef unsigned int u32x4 __attribute__((ext_vector_type(4)));

// workspace layout (float offsets)
#define WS_QVEC 0               // 1024
#define WS_GU   1024            // 16384
#define WS_G    17408           // 16  (Gv)
#define WS_CB   17424           // 16
#define WS_GP   17440           // 64
#define WS_BP   17504           // 64
#define WS_PL   17568           // 4096
#define WS_PM   21664           // 4096
#define WS_PA   25760           // 4194304
#define WS_CTX  4220064         // 65536
#define WS_POOL 4285600         // 65536

__device__ __forceinline__ unsigned int pk2(float a, float b) {
    __hip_bfloat162 h = __float22bfloat162_rn(make_float2(a, b));
    unsigned int r;
    __builtin_memcpy(&r, &h, 4);
    return r;
}

__device__ __forceinline__ const float* rowptr(int gr, int b, const float* cls,
                                               const float* sto, const float* pat) {
    if (gr == 0) return cls + (size_t)b * DD;
    if (gr <= 4) return sto + ((size_t)b * 4 + (gr - 1)) * DD;
    return pat + ((size_t)b * 4096 + (gr - 5)) * DD;
}

// ---------------- prep: qp = Wq*query + bq ----------------
__global__ void k_qvec(const float* __restrict__ query, const float* __restrict__ Wq,
                       const float* __restrict__ bq, float* __restrict__ qvec) {
    int j = blockIdx.x; int lane = threadIdx.x;          // 64 threads
    const float4* wr = reinterpret_cast<const float4*>(Wq + (size_t)j * DD);
    const float4* qr = reinterpret_cast<const float4*>(query);
    float s = 0.f;
#pragma unroll
    for (int k = 0; k < 4; ++k) {
        float4 a = wr[k * 64 + lane];
        float4 q = qr[k * 64 + lane];
        s += a.x * q.x + a.y * q.y + a.z * q.z + a.w * q.w;
    }
#pragma unroll
    for (int m = 1; m < 64; m <<= 1) s += __shfl_xor(s, m, 64);
    if (lane == 0) qvec[j] = s + bq[j];
}

// ---------------- prep: gu = g .* (scale*Wk_h^T qp_h); per-(h,q) partial G, Bu ----------------
__global__ void k_u(const float* __restrict__ Wk, const float* __restrict__ qvec,
                    const float* __restrict__ g, const float* __restrict__ bln,
                    float* __restrict__ gu, float* __restrict__ Gp, float* __restrict__ Bp) {
    int h = blockIdx.x >> 2, q = blockIdx.x & 3;        // 64 blocks, 256 threads
    int tid = threadIdx.x;
    int w = tid >> 6, lane = tid & 63;
    __shared__ float qs[64];
    __shared__ float red[8];
    if (tid < 64) qs[tid] = qvec[h * 64 + tid];
    __syncthreads();
    int d = q * 256 + tid;
    float a = 0.f;
#pragma unroll 8
    for (int i = 0; i < 64; ++i) a += qs[i] * Wk[(size_t)(h * 64 + i) * DD + d];
    float u = a * SCALE;
    float guv = u * g[d];
    gu[(size_t)h * DD + d] = guv;
    float Gv_ = guv, Bv_ = u * bln[d];
#pragma unroll
    for (int m = 1; m < 64; m <<= 1) { Gv_ += __shfl_xor(Gv_, m, 64); Bv_ += __shfl_xor(Bv_, m, 64); }
    if (lane == 0) { red[2 * w] = Gv_; red[2 * w + 1] = Bv_; }
    __syncthreads();
    if (tid == 0) {
        Gp[h * 4 + q] = red[0] + red[2] + red[4] + red[6];
        Bp[h * 4 + q] = red[1] + red[3] + red[5] + red[7];
    }
}

// ---------------- prep: Gv, CB ----------------
__global__ void k_cq(const float* __restrict__ qvec, const float* __restrict__ bk,
                     const float* __restrict__ Gp, const float* __restrict__ Bp,
                     float* __restrict__ Gv, float* __restrict__ CB) {
    int h = threadIdx.x;
    if (h < HH) {
        float G = Gp[h * 4] + Gp[h * 4 + 1] + Gp[h * 4 + 2] + Gp[h * 4 + 3];
        float Bu = Bp[h * 4] + Bp[h * 4 + 1] + Bp[h * 4 + 2] + Bp[h * 4 + 3];
        float s = 0.f;
        for (int i = 0; i < 64; ++i) s += qvec[h * 64 + i] * bk[h * 64 + i];
        Gv[h] = G;
        CB[h] = Bu + s * SCALE;
    }
}

// ---------------- fused main: reads-first async dbuf (m201 ordering) ----------------
// 256 blocks x 512 threads (8 waves, 1 block/CU). 16-row fp32 tiles.
__global__ __launch_bounds__(512, 1) void k_main(
    const float* __restrict__ cls, const float* __restrict__ sto,
    const float* __restrict__ pat, const float* __restrict__ gu,
    const float* __restrict__ Gv, const float* __restrict__ CBv,
    float* __restrict__ pA, float* __restrict__ pl, float* __restrict__ pM) {

    __shared__ __align__(16) float Xf[2 * BUFF];        // 131,584 B fp32 dbuf
    __shared__ __align__(16) f32x4 csr[8][64];          // 8 KB score partials
    __shared__ __align__(16) float sstat[2][16][8];     // [stat][row][wave]
    __shared__ float2 mrs[16];
    __shared__ __align__(8) ushort alds[16 * 32];       // rows 16..31 stay zero

    const int blk = blockIdx.x;
    const int b = blk >> 2, ch = blk & 3;
    const int row0 = ch * CHUNK;
    const int rows = min(CHUNK, LL - row0);
    const int nt = (rows + 15) >> 4;
    const int tid = threadIdx.x;
    const int w = tid >> 6, lane = tid & 63;
    const int lm = lane & 15, lg = lane >> 4;

    if (tid < 256) reinterpret_cast<unsigned int*>(alds)[tid] = 0u;

    // op2 gu B-fragments: head=lm, d = w*128 + s*32 + lg*8 + j
    s16x8 guf[4];
    {
        const float* gubase = gu + (size_t)lm * DD + w * 128 + lg * 8;
#pragma unroll
        for (int s = 0; s < 4; ++s) {
            const float* p = gubase + s * 32;
            u32x4 t;
#pragma unroll
            for (int j = 0; j < 4; ++j) t[j] = pk2(p[2 * j], p[2 * j + 1]);
            s16x8 f; __builtin_memcpy(&f, &t, 16);
            guf[s] = f;
        }
    }
    s16x8 ones;
#pragma unroll
    for (int j = 0; j < 8; ++j) ones[j] = (short)0x3F80;
    const float Gh = Gv[lm], CBh = CBv[lm];

    f32x4 acc[8];
#pragma unroll
    for (int i = 0; i < 8; ++i) acc[i] = (f32x4){0.f, 0.f, 0.f, 0.f};
    float lacc = 0.f, macc = 0.f;

#define ISSUE_TILE(T)                                                              \
    {                                                                              \
        int buf_ = (T) & 1;                                                        \
        _Pragma("unroll")                                                          \
        for (int rr = 0; rr < 2; ++rr) {                                           \
            int rl = 2 * w + rr;                                                   \
            int rloc = (T) * 16 + rl;                                              \
            if (rloc < rows) {                                                     \
                const float* rp = rowptr(row0 + rloc, b, cls, sto, pat);           \
                _Pragma("unroll")                                                  \
                for (int c = 0; c < 4; ++c) {                                      \
                    __builtin_amdgcn_global_load_lds(                              \
                        (const __attribute__((address_space(1))) unsigned int*)    \
                            (rp + c * 256 + lane * 4),                             \
                        (__attribute__((address_space(3))) unsigned int*)          \
                            (&Xf[buf_ * BUFF + rl * XROWF + c * 256]),             \
                        16, 0, 0);                                                 \
                }                                                                  \
            }                                                                      \
        }                                                                          \
    }

    __syncthreads();          // alds init visible
    ISSUE_TILE(0);
    asm volatile("s_waitcnt vmcnt(0)" ::: "memory");
    __builtin_amdgcn_s_barrier();   // tile 0 landed

    for (int t = 0; t < nt; ++t) {
        const int buf = t & 1;

        // ---- step 1: ALL Xf[buf] reads -> registers (before any new DMA issue) ----
        s16x8 afr[4];                 // op2 A-frags: row lm, d = w*128 + s*32 + lg*8
        {
            const float* Ab = &Xf[buf * BUFF + lm * XROWF + w * 128 + lg * 8];
#pragma unroll
            for (int s = 0; s < 4; ++s) {
                float4 x0 = *reinterpret_cast<const float4*>(Ab + s * 32);
                float4 x1 = *reinterpret_cast<const float4*>(Ab + s * 32 + 4);
                u32x4 tt;
                tt[0] = pk2(x0.x, x0.y); tt[1] = pk2(x0.z, x0.w);
                tt[2] = pk2(x1.x, x1.y); tt[3] = pk2(x1.z, x1.w);
                s16x8 f; __builtin_memcpy(&f, &tt, 16);
                afr[s] = f;
            }
        }
        s16x8 bfr[8];                 // op4 B-frags: k=lg*8+j -> row (lg&1)*8+j (lg<2), col w*128+dt*16+lm
        {
            const float* Bb = &Xf[buf * BUFF + (lg & 1) * 8 * XROWF + w * 128 + lm];
            bool act = lg < 2;
#pragma unroll
            for (int dt = 0; dt < 8; ++dt) {
                float bx[8];
#pragma unroll
                for (int j = 0; j < 8; ++j) bx[j] = act ? Bb[j * XROWF + dt * 16] : 0.f;
                u32x4 tb;
                tb[0] = pk2(bx[0], bx[1]); tb[1] = pk2(bx[2], bx[3]);
                tb[2] = pk2(bx[4], bx[5]); tb[3] = pk2(bx[6], bx[7]);
                s16x8 f; __builtin_memcpy(&f, &tb, 16);
                bfr[dt] = f;
            }
        }

        // ---- step 2: issue next tile's DMA (rides across barriers) ----
        if (t + 1 < nt) ISSUE_TILE(t + 1);

        // ---- step 3: op2 MFMAs (pure reg) ----
        {
            f32x4 c0 = {0.f,0.f,0.f,0.f}, q0 = {0.f,0.f,0.f,0.f}, m0 = {0.f,0.f,0.f,0.f};
#pragma unroll
            for (int s = 0; s < 4; ++s) {
                c0 = __builtin_amdgcn_mfma_f32_16x16x32_bf16(afr[s], guf[s], c0, 0, 0, 0);
                q0 = __builtin_amdgcn_mfma_f32_16x16x32_bf16(afr[s], afr[s], q0, 0, 0, 0);
                m0 = __builtin_amdgcn_mfma_f32_16x16x32_bf16(afr[s], ones,   m0, 0, 0, 0);
            }
            csr[w][lane] = c0;
            if (lg == (lm >> 2)) sstat[0][lm][w] = q0[lm & 3];
            if (lm == 0) {
#pragma unroll
                for (int i = 0; i < 4; ++i) sstat[1][lg * 4 + i][w] = m0[i];
            }
        }
        asm volatile("s_waitcnt lgkmcnt(0)" ::: "memory");
        __builtin_amdgcn_s_barrier();                       // csr/sstat visible

        // ---- step 4: finalize (redundant per wave) ----
        if (lane < 16) {
            const float4* q4 = reinterpret_cast<const float4*>(&sstat[0][lane][0]);
            float4 qa = q4[0], qb = q4[1];
            const float4* m4 = reinterpret_cast<const float4*>(&sstat[1][lane][0]);
            float4 ma = m4[0], mb = m4[1];
            float s2 = qa.x + qa.y + qa.z + qa.w + qb.x + qb.y + qb.z + qb.w;
            float s1 = ma.x + ma.y + ma.z + ma.w + mb.x + mb.y + mb.z + mb.w;
            float mean = s1 * (1.f / 1024.f);
            float var  = s2 * (1.f / 1024.f) - mean * mean;
            float rstd = rsqrtf(var + LN_EPS);
            mrs[lane] = make_float2(rstd, -mean * rstd);
        }
        asm volatile("s_waitcnt lgkmcnt(0)" ::: "memory");
        __builtin_amdgcn_sched_barrier(0);
        {
            f32x4 dv = csr[0][lane];
#pragma unroll
            for (int wp = 1; wp < 8; ++wp) dv += csr[wp][lane];
            int rbase = lg * 4;
            float al[4];
#pragma unroll
            for (int i = 0; i < 4; ++i) {
                float2 mr = mrs[rbase + i];
                float sc = dv[i] * mr.x + (mr.y * Gh + CBh);
                bool vld = (t * 16 + rbase + i) < rows;
                float p = vld ? __expf(sc) : 0.f;
                lacc += p;
                macc += p * mr.y;
                al[i] = p * mr.x;
            }
            *reinterpret_cast<unsigned int*>(&alds[lm * 32 + rbase])     = pk2(al[0], al[1]);
            *reinterpret_cast<unsigned int*>(&alds[lm * 32 + rbase + 2]) = pk2(al[2], al[3]);
        }
        asm volatile("s_waitcnt lgkmcnt(0)" ::: "memory");
        __builtin_amdgcn_sched_barrier(0);

        // ---- step 5: op4 MFMAs (af from alds; B-frags already in regs) ----
        {
            s16x8 af = *reinterpret_cast<const s16x8*>(&alds[lm * 32 + lg * 8]);
#pragma unroll
            for (int dt = 0; dt < 8; ++dt)
                acc[dt] = __builtin_amdgcn_mfma_f32_16x16x32_bf16(af, bfr[dt], acc[dt], 0, 0, 0);
        }

        // ---- step 6: next tile landed + all waves done reading buf ----
        asm volatile("s_waitcnt vmcnt(0) lgkmcnt(0)" ::: "memory");
        __builtin_amdgcn_s_barrier();
    }

    // write partial A  (pA[blk][h][1024])
    size_t pabase = ((size_t)blk << 14);
#pragma unroll
    for (int dt = 0; dt < 8; ++dt) {
#pragma unroll
        for (int i = 0; i < 4; ++i) {
            int h = lg * 4 + i;
            pA[pabase + ((size_t)h << 10) + w * 128 + dt * 16 + lm] = acc[dt][i];
        }
    }
    if (w == 0) {
        lacc += __shfl_xor(lacc, 16, 64); lacc += __shfl_xor(lacc, 32, 64);
        macc += __shfl_xor(macc, 16, 64); macc += __shfl_xor(macc, 32, 64);
        if (lane < 16) {
            pl[blk * 16 + lane] = lacc;
            pM[blk * 16 + lane] = -macc;
        }
    }
#undef ISSUE_TILE
}

// ---------------- combine partials: sbar = (g.*(A - M))/l + b  (overlays pA ch=0) ----------------
__global__ void k_comb(float* __restrict__ pA, const float* __restrict__ pl,
                       const float* __restrict__ pM, const float* __restrict__ g,
                       const float* __restrict__ bln) {
    int blk = blockIdx.x; int b = blk >> 4; int h = blk & 15; int tid = threadIdx.x;
    float l = 0.f, M = 0.f;
#pragma unroll
    for (int ch = 0; ch < NCH; ++ch) {
        l += pl[(b * NCH + ch) * 16 + h];
        M += pM[(b * NCH + ch) * 16 + h];
    }
    float inv = 1.f / l;
    float4 s = make_float4(0.f, 0.f, 0.f, 0.f);
#pragma unroll
    for (int ch = 0; ch < NCH; ++ch) {
        const float4* p4 = reinterpret_cast<const float4*>(
            pA + (((size_t)(b * NCH + ch) * 16 + h) << 10));
        float4 v = p4[tid];
        s.x += v.x; s.y += v.y; s.z += v.z; s.w += v.w;
    }
    float4 g4 = *reinterpret_cast<const float4*>(&g[tid * 4]);
    float4 b4 = *reinterpret_cast<const float4*>(&bln[tid * 4]);
    float4 o;
    o.x = g4.x * (s.x - M) * inv + b4.x;
    o.y = g4.y * (s.y - M) * inv + b4.y;
    o.z = g4.z * (s.z - M) * inv + b4.z;
    o.w = g4.w * (s.w - M) * inv + b4.w;
    float4* dst = reinterpret_cast<float4*>(pA + (((size_t)(b * NCH) * 16 + h) << 10));
    dst[tid] = o;
}

// ---------------- ctx = Wv_h * sbar_h + bv ----------------
__global__ void k_ctx(const float* __restrict__ Wv, const float* __restrict__ bv,
                      const float* __restrict__ pA, float* __restrict__ ctx) {
    int j = blockIdx.x; int h = j >> 6;
    int w = threadIdx.x >> 6, lane = threadIdx.x & 63;
    const float4* wr = reinterpret_cast<const float4*>(Wv + (size_t)j * DD);
    float4 wv[4];
#pragma unroll
    for (int k = 0; k < 4; ++k) wv[k] = wr[k * 64 + lane];
    float bvj = bv[j];
    for (int bb2 = w * 16; bb2 < w * 16 + 16; ++bb2) {
        const float4* sr = reinterpret_cast<const float4*>(
            pA + (((size_t)(bb2 * NCH) * 16 + h) << 10));
        float s = 0.f;
#pragma unroll
        for (int k = 0; k < 4; ++k) {
            float4 v = sr[k * 64 + lane];
            s += wv[k].x * v.x + wv[k].y * v.y + wv[k].z * v.z + wv[k].w * v.w;
        }
#pragma unroll
        for (int m = 1; m < 64; m <<= 1) s += __shfl_xor(s, m, 64);
        if (lane == 0) ctx[(size_t)bb2 * DD + j] = s + bvj;
    }
}

// ---------------- pooled = Wo * ctx + bo ----------------
__global__ void k_pool(const float* __restrict__ Wo, const float* __restrict__ bo,
                       const float* __restrict__ ctx, float* __restrict__ pooled) {
    int j = blockIdx.x;
    int w = threadIdx.x >> 6, lane = threadIdx.x & 63;
    const float4* wr = reinterpret_cast<const float4*>(Wo + (size_t)j * DD);
    float4 wv[4];
#pragma unroll
    for (int k = 0; k < 4; ++k) wv[k] = wr[k * 64 + lane];
    float boj = bo[j];
    for (int bb2 = w * 16; bb2 < w * 16 + 16; ++bb2) {
        const float4* cr4 = reinterpret_cast<const float4*>(ctx + (size_t)bb2 * DD);
        float s = 0.f;
#pragma unroll
        for (int k = 0; k < 4; ++k) {
            float4 v = cr4[k * 64 + lane];
            s += wv[k].x * v.x + wv[k].y * v.y + wv[k].z * v.z + wv[k].w * v.w;
        }
#pragma unroll
        for (int m = 1; m < 64; m <<= 1) s += __shfl_xor(s, m, 64);
        if (lane == 0) pooled[(size_t)bb2 * DD + j] = s + boj;
    }
}

// ---------------- final LN + classifier head ----------------
__global__ void k_head(const float* __restrict__ pooled, const float* __restrict__ g2,
                       const float* __restrict__ b2, const float* __restrict__ Wp,
                       const float* __restrict__ bp, float* __restrict__ out) {
    int b = blockIdx.x; int tid = threadIdx.x;
    __shared__ float pln[DD];
    __shared__ float red[8];
    const float4* pr = reinterpret_cast<const float4*>(pooled + (size_t)b * DD);
    float4 v = pr[tid];
    float s1 = v.x + v.y + v.z + v.w;
    float s2 = v.x * v.x + v.y * v.y + v.z * v.z + v.w * v.w;
#pragma unroll
    for (int m = 1; m < 64; m <<= 1) { s1 += __shfl_xor(s1, m, 64); s2 += __shfl_xor(s2, m, 64); }
    int w = tid >> 6, lane = tid & 63;
    if (lane == 0) { red[2 * w] = s1; red[2 * w + 1] = s2; }
    __syncthreads();
    s1 = red[0] + red[2] + red[4] + red[6];
    s2 = red[1] + red[3] + red[5] + red[7];
    float mean = s1 * (1.f / 1024.f);
    float var  = s2 * (1.f / 1024.f) - mean * mean;
    float rstd = rsqrtf(var + LN_EPS);
    int d0 = tid * 4;
    pln[d0 + 0] = (v.x - mean) * rstd * g2[d0 + 0] + b2[d0 + 0];
    pln[d0 + 1] = (v.y - mean) * rstd * g2[d0 + 1] + b2[d0 + 1];
    pln[d0 + 2] = (v.z - mean) * rstd * g2[d0 + 2] + b2[d0 + 2];
    pln[d0 + 3] = (v.w - mean) * rstd * g2[d0 + 3] + b2[d0 + 3];
    __syncthreads();
    int q = tid & 15, c = tid >> 4;
    if (c < 14) {
        float s = 0.f;
#pragma unroll 8
        for (int i = 0; i < 64; ++i) {
            int d = i * 16 + q;
            s += pln[d] * Wp[c * DD + d];
        }
#pragma unroll
        for (int m = 1; m < 16; m <<= 1) s += __shfl_xor(s, m, 64);
        if (q == 0) out[b * 14 + c] = s + bp[c];
    }
}

extern "C" void kernel_launch(void* const* d_in, const int* in_sizes, int n_in,
                              void* d_out, int out_size, void* d_ws, size_t ws_size,
                              hipStream_t stream) {
    const float* cls   = (const float*)d_in[0];
    const float* sto   = (const float*)d_in[1];
    const float* pat   = (const float*)d_in[2];
    const float* query = (const float*)d_in[3];
    const float* g     = (const float*)d_in[4];
    const float* bln   = (const float*)d_in[5];
    const float* Wq    = (const float*)d_in[6];
    const float* Wk    = (const float*)d_in[7];
    const float* Wv    = (const float*)d_in[8];
    const float* bq    = (const float*)d_in[9];
    const float* bk    = (const float*)d_in[10];
    const float* bv    = (const float*)d_in[11];
    const float* Wo    = (const float*)d_in[12];
    const float* bo    = (const float*)d_in[13];
    const float* g2    = (const float*)d_in[14];
    const float* b2    = (const float*)d_in[15];
    const float* Wp    = (const float*)d_in[16];
    const float* bp    = (const float*)d_in[17];

    float* ws     = (float*)d_ws;
    float* qvec   = ws + WS_QVEC;
    float* gu     = ws + WS_GU;
    float* Gv     = ws + WS_G;
    float* CB     = ws + WS_CB;
    float* Gp     = ws + WS_GP;
    float* Bp     = ws + WS_BP;
    float* pl     = ws + WS_PL;
    float* pM     = ws + WS_PM;
    float* pA     = ws + WS_PA;
    float* ctx    = ws + WS_CTX;
    float* pooled = ws + WS_POOL;
    float* out    = (float*)d_out;

    hipLaunchKernelGGL(k_qvec, dim3(1024), dim3(64), 0, stream, query, Wq, bq, qvec);
    hipLaunchKernelGGL(k_u,    dim3(64),   dim3(256), 0, stream, Wk, qvec, g, bln, gu, Gp, Bp);
    hipLaunchKernelGGL(k_cq,   dim3(1),    dim3(64), 0, stream, qvec, bk, Gp, Bp, Gv, CB);
    hipLaunchKernelGGL(k_main, dim3(BB * NCH), dim3(512), 0, stream,
                       cls, sto, pat, gu, Gv, CB, pA, pl, pM);
    hipLaunchKernelGGL(k_comb, dim3(BB * HH), dim3(256), 0, stream, pA, pl, pM, g, bln);
    hipLaunchKernelGGL(k_ctx,  dim3(1024), dim3(256), 0, stream, Wv, bv, pA, ctx);
    hipLaunchKernelGGL(k_pool, dim3(1024), dim3(256), 0, stream, Wo, bo, ctx, pooled);
    hipLaunchKernelGGL(k_head, dim3(64),   dim3(256), 0, stream, pooled, g2, b2, Wp, bp, out);
}

// Round 10
// 284.531 us; speedup vs baseline: 1.5055x; 1.3134x over previous
//
#include <hip/hip_runtime.h>
#include <hip/hip_bf16.h>

#define BB 64
#define DD 1024
#define HH 16
#define LL 4101          // 1 + 4 + 4096
#define SCALE 0.125f
#define LN_EPS 1e-5f
#define RGS 4112         // padded row-group stride (elem): 4112%64=16 -> op4 conflict-free

typedef float  f32x4 __attribute__((ext_vector_type(4)));
typedef short  s16x8 __attribute__((ext_vector_type(8)));
typedef unsigned int u32x4 __attribute__((ext_vector_type(4)));

// static workspace layout (float offsets), sized for nch<=12
#define WS_QVEC 0               // 1024
#define WS_GU   1024            // 16384
#define WS_G    17408           // 16
#define WS_CB   17424           // 16
#define WS_GP   17440           // 64
#define WS_BP   17504           // 64
#define WS_PL   17568           // up to 12288
#define WS_PM   29856           // up to 12288
#define WS_PA   42144           // up to 64*12*16*1024

__device__ __forceinline__ unsigned int pk2(float a, float b) {
    __hip_bfloat162 h = __float22bfloat162_rn(make_float2(a, b));
    unsigned int r;
    __builtin_memcpy(&r, &h, 4);
    return r;
}

__device__ __forceinline__ const float* rowptr(int gr, int b, const float* cls,
                                               const float* sto, const float* pat) {
    if (gr == 0) return cls + (size_t)b * DD;
    if (gr <= 4) return sto + ((size_t)b * 4 + (gr - 1)) * DD;
    return pat + ((size_t)b * 4096 + (gr - 5)) * DD;
}

// ---------------- prep: qp = Wq*query + bq ----------------
__global__ void k_qvec(const float* __restrict__ query, const float* __restrict__ Wq,
                       const float* __restrict__ bq, float* __restrict__ qvec) {
    int j = blockIdx.x; int lane = threadIdx.x;          // 64 threads
    const float4* wr = reinterpret_cast<const float4*>(Wq + (size_t)j * DD);
    const float4* qr = reinterpret_cast<const float4*>(query);
    float s = 0.f;
#pragma unroll
    for (int k = 0; k < 4; ++k) {
        float4 a = wr[k * 64 + lane];
        float4 q = qr[k * 64 + lane];
        s += a.x * q.x + a.y * q.y + a.z * q.z + a.w * q.w;
    }
#pragma unroll
    for (int m = 1; m < 64; m <<= 1) s += __shfl_xor(s, m, 64);
    if (lane == 0) qvec[j] = s + bq[j];
}

// ---------------- prep: gu = g .* (scale*Wk_h^T qp_h); per-(h,q) partial G, Bu ----------------
__global__ void k_u(const float* __restrict__ Wk, const float* __restrict__ qvec,
                    const float* __restrict__ g, const float* __restrict__ bln,
                    float* __restrict__ gu, float* __restrict__ Gp, float* __restrict__ Bp) {
    int h = blockIdx.x >> 2, q = blockIdx.x & 3;        // 64 blocks, 256 threads
    int tid = threadIdx.x;
    int w = tid >> 6, lane = tid & 63;
    __shared__ float qs[64];
    __shared__ float red[8];
    if (tid < 64) qs[tid] = qvec[h * 64 + tid];
    __syncthreads();
    int d = q * 256 + tid;
    float a = 0.f;
#pragma unroll 8
    for (int i = 0; i < 64; ++i) a += qs[i] * Wk[(size_t)(h * 64 + i) * DD + d];
    float u = a * SCALE;
    float guv = u * g[d];
    gu[(size_t)h * DD + d] = guv;
    float Gv_ = guv, Bv_ = u * bln[d];
#pragma unroll
    for (int m = 1; m < 64; m <<= 1) { Gv_ += __shfl_xor(Gv_, m, 64); Bv_ += __shfl_xor(Bv_, m, 64); }
    if (lane == 0) { red[2 * w] = Gv_; red[2 * w + 1] = Bv_; }
    __syncthreads();
    if (tid == 0) {
        Gp[h * 4 + q] = red[0] + red[2] + red[4] + red[6];
        Bp[h * 4 + q] = red[1] + red[3] + red[5] + red[7];
    }
}

// ---------------- prep: Gv, CB ----------------
__global__ void k_cq(const float* __restrict__ qvec, const float* __restrict__ bk,
                     const float* __restrict__ Gp, const float* __restrict__ Bp,
                     float* __restrict__ Gv, float* __restrict__ CB) {
    int h = threadIdx.x;
    if (h < HH) {
        float G = Gp[h * 4] + Gp[h * 4 + 1] + Gp[h * 4 + 2] + Gp[h * 4 + 3];
        float Bu = Bp[h * 4] + Bp[h * 4 + 1] + Bp[h * 4 + 2] + Bp[h * 4 + 3];
        float s = 0.f;
        for (int i = 0; i < 64; ++i) s += qvec[h * 64 + i] * bk[h * 64 + i];
        Gv[h] = G;
        CB[h] = Bu + s * SCALE;
    }
}

// ---------------- fused main: 4 waves, 16-row single-buffer tiles, 3 blocks/CU ----------------
__global__ __launch_bounds__(256, 3) void k_main(
    const float* __restrict__ cls, const float* __restrict__ sto,
    const float* __restrict__ pat, const float* __restrict__ gu,
    const float* __restrict__ Gv, const float* __restrict__ CBv,
    float* __restrict__ pA, float* __restrict__ pl, float* __restrict__ pM,
    int nch, int chunk) {

    __shared__ __align__(16) ushort Xs[4 * RGS];       // 32,896 B subtiled [r>>2][d>>4][r&3][d&15]
    __shared__ __align__(16) f32x4 csr[4][64];         // 4 KB score partials
    __shared__ __align__(8) ushort alds[512];          // 1 KB alpha bf16 [16h][32k], k 16..31 stay 0
    __shared__ float2 mrs[16];                         // (rstd, -mean*rstd)

    const int blk = blockIdx.x;
    const int b = blk / nch, ch = blk - b * nch;
    const int row0 = ch * chunk;
    const int rows = min(chunk, LL - row0);
    const int nt = (rows + 15) >> 4;
    const int tid = threadIdx.x;
    const int w = tid >> 6, lane = tid & 63;
    const int lm = lane & 15, lg = lane >> 4;

    if (tid < 256) reinterpret_cast<unsigned int*>(alds)[tid] = 0u;

    // op2 gu B-fragments: head=lm, d = w*256 + s*32 + lg*8 + j
    s16x8 guf[8];
    {
        const float* gubase = gu + (size_t)lm * DD + w * 256 + lg * 8;
#pragma unroll
        for (int s = 0; s < 8; ++s) {
            const float* p = gubase + s * 32;
            u32x4 t;
#pragma unroll
            for (int j = 0; j < 4; ++j) t[j] = pk2(p[2 * j], p[2 * j + 1]);
            s16x8 f; __builtin_memcpy(&f, &t, 16);
            guf[s] = f;
        }
    }
    const float Gh = Gv[lm], CBh = CBv[lm];

    f32x4 acc[16];
#pragma unroll
    for (int i = 0; i < 16; ++i) acc[i] = (f32x4){0.f, 0.f, 0.f, 0.f};
    float lacc = 0.f, macc = 0.f;

    // op2 A-frag base: row lm, d = w*256 + s*32 + lg*8
    const int C0 = (lm >> 2) * RGS + w * 1024 + (lg >> 1) * 64 + (lm & 3) * 16 + (lg & 1) * 8;
    const bool act = lg < 2;                            // op4: k=lg*8+j real only for lg<2

    __syncthreads();                                    // alds init visible

    for (int t = 0; t < nt; ++t) {
        // ---- stage: 4 rows per wave (load, LN stats, convert, subtiled write) ----
#pragma unroll 2
        for (int rr = 0; rr < 4; ++rr) {
            int rl = w * 4 + rr;
            int rloc = t * 16 + rl;
            bool valid = rloc < rows;
            float4 v[4];
#pragma unroll
            for (int it = 0; it < 4; ++it) v[it] = make_float4(0.f, 0.f, 0.f, 0.f);
            if (valid) {
                const float4* s4 = reinterpret_cast<const float4*>(
                    rowptr(row0 + rloc, b, cls, sto, pat));
#pragma unroll
                for (int it = 0; it < 4; ++it) v[it] = s4[it * 64 + lane];
            }
            float s1 = 0.f, s2 = 0.f;
#pragma unroll
            for (int it = 0; it < 4; ++it) {
                float4 q = v[it];
                s1 += q.x + q.y + q.z + q.w;
                s2 += q.x * q.x + q.y * q.y + q.z * q.z + q.w * q.w;
                uint2 pk;
                pk.x = pk2(q.x, q.y);
                pk.y = pk2(q.z, q.w);
                int d0 = 4 * (it * 64 + lane);
                int elem = (rl >> 2) * RGS + (d0 >> 4) * 64 + (rl & 3) * 16 + (d0 & 15);
                *reinterpret_cast<uint2*>(&Xs[elem]) = pk;
            }
#pragma unroll
            for (int m = 1; m < 64; m <<= 1) {
                s1 += __shfl_xor(s1, m, 64);
                s2 += __shfl_xor(s2, m, 64);
            }
            if (lane == 0) {
                float mean = s1 * (1.f / 1024.f);
                float var = s2 * (1.f / 1024.f) - mean * mean;
                float rstd = rsqrtf(var + LN_EPS);
                mrs[rl] = make_float2(rstd, -mean * rstd);
            }
        }
        __syncthreads();                                 // B1

        // ---- op2: score partials, 8 MFMAs (16 rows x 256-d slice per wave) ----
        {
            f32x4 c0 = {0.f, 0.f, 0.f, 0.f};
#pragma unroll
            for (int s = 0; s < 8; ++s) {
                s16x8 a0 = *reinterpret_cast<const s16x8*>(&Xs[C0 + s * 128]);
                c0 = __builtin_amdgcn_mfma_f32_16x16x32_bf16(a0, guf[s], c0, 0, 0, 0);
            }
            csr[w][lane] = c0;
        }
        __syncthreads();                                 // B2

        // ---- finalize (all 4 waves redundantly) ----
        {
            f32x4 dv = csr[0][lane];
#pragma unroll
            for (int wp = 1; wp < 4; ++wp) dv += csr[wp][lane];
            int rbase = lg * 4;
            float al[4];
#pragma unroll
            for (int i = 0; i < 4; ++i) {
                float2 mr = mrs[rbase + i];
                float sc = dv[i] * mr.x + (mr.y * Gh + CBh);
                bool vld = (t * 16 + rbase + i) < rows;
                float p = vld ? __expf(sc) : 0.f;
                lacc += p;
                macc += p * mr.y;
                al[i] = p * mr.x;
            }
            *reinterpret_cast<unsigned int*>(&alds[lm * 32 + rbase])     = pk2(al[0], al[1]);
            *reinterpret_cast<unsigned int*>(&alds[lm * 32 + rbase + 2]) = pk2(al[2], al[3]);
        }
        asm volatile("s_waitcnt lgkmcnt(0)" ::: "memory");  // own-wave alds visibility
        __builtin_amdgcn_sched_barrier(0);

        // ---- op4: acc[h][d] += alpha^T . X  (k 0..15 real, 16..31 zero A-side) ----
        {
            s16x8 af = *reinterpret_cast<const s16x8*>(&alds[lm * 32 + lg * 8]);
#pragma unroll
            for (int dt = 0; dt < 16; ++dt) {
                s16x8 bfrag;
#pragma unroll
                for (int j = 0; j < 8; ++j) {
                    // r = lg*8 + j (lg<2), d = w*256 + dt*16 + lm
                    int e = (lg * 2 + (j >> 2)) * RGS + (w * 16 + dt) * 64 + (j & 3) * 16 + lm;
                    bfrag[j] = act ? (short)Xs[e] : (short)0;
                }
                acc[dt] = __builtin_amdgcn_mfma_f32_16x16x32_bf16(af, bfrag, acc[dt], 0, 0, 0);
            }
        }
        __syncthreads();                                 // B3 (protect Xs)
    }

    // write partial A  (pA[blk][h][1024])
    size_t pabase = ((size_t)blk << 14);
#pragma unroll
    for (int dt = 0; dt < 16; ++dt) {
#pragma unroll
        for (int i = 0; i < 4; ++i) {
            int h = lg * 4 + i;
            pA[pabase + ((size_t)h << 10) + w * 256 + dt * 16 + lm] = acc[dt][i];
        }
    }
    if (w == 0) {
        lacc += __shfl_xor(lacc, 16, 64); lacc += __shfl_xor(lacc, 32, 64);
        macc += __shfl_xor(macc, 16, 64); macc += __shfl_xor(macc, 32, 64);
        if (lane < 16) {
            pl[blk * 16 + lane] = lacc;
            pM[blk * 16 + lane] = -macc;
        }
    }
}

// ---------------- combine partials: sbar = (g.*(A - M))/l + b  (overlays pA ch=0) ----------------
__global__ void k_comb(float* __restrict__ pA, const float* __restrict__ pl,
                       const float* __restrict__ pM, const float* __restrict__ g,
                       const float* __restrict__ bln, int nch) {
    int blk = blockIdx.x; int b = blk >> 4; int h = blk & 15; int tid = threadIdx.x;
    float l = 0.f, M = 0.f;
    for (int ch = 0; ch < nch; ++ch) {
        l += pl[(b * nch + ch) * 16 + h];
        M += pM[(b * nch + ch) * 16 + h];
    }
    float inv = 1.f / l;
    float4 s = make_float4(0.f, 0.f, 0.f, 0.f);
    for (int ch = 0; ch < nch; ++ch) {
        const float4* p4 = reinterpret_cast<const float4*>(
            pA + (((size_t)(b * nch + ch) * 16 + h) << 10));
        float4 v = p4[tid];
        s.x += v.x; s.y += v.y; s.z += v.z; s.w += v.w;
    }
    float4 g4 = *reinterpret_cast<const float4*>(&g[tid * 4]);
    float4 b4 = *reinterpret_cast<const float4*>(&bln[tid * 4]);
    float4 o;
    o.x = g4.x * (s.x - M) * inv + b4.x;
    o.y = g4.y * (s.y - M) * inv + b4.y;
    o.z = g4.z * (s.z - M) * inv + b4.z;
    o.w = g4.w * (s.w - M) * inv + b4.w;
    float4* dst = reinterpret_cast<float4*>(pA + (((size_t)(b * nch) * 16 + h) << 10));
    dst[tid] = o;
}

// ---------------- ctx = Wv_h * sbar_h + bv ----------------
__global__ void k_ctx(const float* __restrict__ Wv, const float* __restrict__ bv,
                      const float* __restrict__ pA, float* __restrict__ ctx, int nch) {
    int j = blockIdx.x; int h = j >> 6;
    int w = threadIdx.x >> 6, lane = threadIdx.x & 63;
    const float4* wr = reinterpret_cast<const float4*>(Wv + (size_t)j * DD);
    float4 wv[4];
#pragma unroll
    for (int k = 0; k < 4; ++k) wv[k] = wr[k * 64 + lane];
    float bvj = bv[j];
    for (int bb2 = w * 16; bb2 < w * 16 + 16; ++bb2) {
        const float4* sr = reinterpret_cast<const float4*>(
            pA + (((size_t)(bb2 * nch) * 16 + h) << 10));
        float s = 0.f;
#pragma unroll
        for (int k = 0; k < 4; ++k) {
            float4 v = sr[k * 64 + lane];
            s += wv[k].x * v.x + wv[k].y * v.y + wv[k].z * v.z + wv[k].w * v.w;
        }
#pragma unroll
        for (int m = 1; m < 64; m <<= 1) s += __shfl_xor(s, m, 64);
        if (lane == 0) ctx[(size_t)bb2 * DD + j] = s + bvj;
    }
}

// ---------------- pooled = Wo * ctx + bo ----------------
__global__ void k_pool(const float* __restrict__ Wo, const float* __restrict__ bo,
                       const float* __restrict__ ctx, float* __restrict__ pooled) {
    int j = blockIdx.x;
    int w = threadIdx.x >> 6, lane = threadIdx.x & 63;
    const float4* wr = reinterpret_cast<const float4*>(Wo + (size_t)j * DD);
    float4 wv[4];
#pragma unroll
    for (int k = 0; k < 4; ++k) wv[k] = wr[k * 64 + lane];
    float boj = bo[j];
    for (int bb2 = w * 16; bb2 < w * 16 + 16; ++bb2) {
        const float4* cr4 = reinterpret_cast<const float4*>(ctx + (size_t)bb2 * DD);
        float s = 0.f;
#pragma unroll
        for (int k = 0; k < 4; ++k) {
            float4 v = cr4[k * 64 + lane];
            s += wv[k].x * v.x + wv[k].y * v.y + wv[k].z * v.z + wv[k].w * v.w;
        }
#pragma unroll
        for (int m = 1; m < 64; m <<= 1) s += __shfl_xor(s, m, 64);
        if (lane == 0) pooled[(size_t)bb2 * DD + j] = s + boj;
    }
}

// ---------------- final LN + classifier head ----------------
__global__ void k_head(const float* __restrict__ pooled, const float* __restrict__ g2,
                       const float* __restrict__ b2, const float* __restrict__ Wp,
                       const float* __restrict__ bp, float* __restrict__ out) {
    int b = blockIdx.x; int tid = threadIdx.x;
    __shared__ float pln[DD];
    __shared__ float red[8];
    const float4* pr = reinterpret_cast<const float4*>(pooled + (size_t)b * DD);
    float4 v = pr[tid];
    float s1 = v.x + v.y + v.z + v.w;
    float s2 = v.x * v.x + v.y * v.y + v.z * v.z + v.w * v.w;
#pragma unroll
    for (int m = 1; m < 64; m <<= 1) { s1 += __shfl_xor(s1, m, 64); s2 += __shfl_xor(s2, m, 64); }
    int w = tid >> 6, lane = tid & 63;
    if (lane == 0) { red[2 * w] = s1; red[2 * w + 1] = s2; }
    __syncthreads();
    s1 = red[0] + red[2] + red[4] + red[6];
    s2 = red[1] + red[3] + red[5] + red[7];
    float mean = s1 * (1.f / 1024.f);
    float var  = s2 * (1.f / 1024.f) - mean * mean;
    float rstd = rsqrtf(var + LN_EPS);
    int d0 = tid * 4;
    pln[d0 + 0] = (v.x - mean) * rstd * g2[d0 + 0] + b2[d0 + 0];
    pln[d0 + 1] = (v.y - mean) * rstd * g2[d0 + 1] + b2[d0 + 1];
    pln[d0 + 2] = (v.z - mean) * rstd * g2[d0 + 2] + b2[d0 + 2];
    pln[d0 + 3] = (v.w - mean) * rstd * g2[d0 + 3] + b2[d0 + 3];
    __syncthreads();
    int q = tid & 15, c = tid >> 4;
    if (c < 14) {
        float s = 0.f;
#pragma unroll 8
        for (int i = 0; i < 64; ++i) {
            int d = i * 16 + q;
            s += pln[d] * Wp[c * DD + d];
        }
#pragma unroll
        for (int m = 1; m < 16; m <<= 1) s += __shfl_xor(s, m, 64);
        if (q == 0) out[b * 14 + c] = s + bp[c];
    }
}

extern "C" void kernel_launch(void* const* d_in, const int* in_sizes, int n_in,
                              void* d_out, int out_size, void* d_ws, size_t ws_size,
                              hipStream_t stream) {
    const float* cls   = (const float*)d_in[0];
    const float* sto   = (const float*)d_in[1];
    const float* pat   = (const float*)d_in[2];
    const float* query = (const float*)d_in[3];
    const float* g     = (const float*)d_in[4];
    const float* bln   = (const float*)d_in[5];
    const float* Wq    = (const float*)d_in[6];
    const float* Wk    = (const float*)d_in[7];
    const float* Wv    = (const float*)d_in[8];
    const float* bq    = (const float*)d_in[9];
    const float* bk    = (const float*)d_in[10];
    const float* bv    = (const float*)d_in[11];
    const float* Wo    = (const float*)d_in[12];
    const float* bo    = (const float*)d_in[13];
    const float* g2    = (const float*)d_in[14];
    const float* b2    = (const float*)d_in[15];
    const float* Wp    = (const float*)d_in[16];
    const float* bp    = (const float*)d_in[17];

    // pick nch by available workspace: nch=12 needs ~51 MB, nch=8 ~34.3 MB (proven safe)
    size_t need12 = ((size_t)WS_PA + (size_t)64 * 12 * 16 * 1024 + 2 * 65536) * 4;
    int nch = (ws_size >= need12) ? 12 : 8;
    int chunk = (LL + nch - 1) / nch;

    float* ws     = (float*)d_ws;
    float* qvec   = ws + WS_QVEC;
    float* gu     = ws + WS_GU;
    float* Gv     = ws + WS_G;
    float* CB     = ws + WS_CB;
    float* Gp     = ws + WS_GP;
    float* Bp     = ws + WS_BP;
    float* pl     = ws + WS_PL;
    float* pM     = ws + WS_PM;
    float* pA     = ws + WS_PA;
    float* ctx    = pA + (size_t)64 * nch * 16 * 1024;
    float* pooled = ctx + 65536;
    float* out    = (float*)d_out;

    hipLaunchKernelGGL(k_qvec, dim3(1024), dim3(64), 0, stream, query, Wq, bq, qvec);
    hipLaunchKernelGGL(k_u,    dim3(64),   dim3(256), 0, stream, Wk, qvec, g, bln, gu, Gp, Bp);
    hipLaunchKernelGGL(k_cq,   dim3(1),    dim3(64), 0, stream, qvec, bk, Gp, Bp, Gv, CB);
    hipLaunchKernelGGL(k_main, dim3(BB * nch), dim3(256), 0, stream,
                       cls, sto, pat, gu, Gv, CB, pA, pl, pM, nch, chunk);
    hipLaunchKernelGGL(k_comb, dim3(BB * HH), dim3(256), 0, stream, pA, pl, pM, g, bln, nch);
    hipLaunchKernelGGL(k_ctx,  dim3(1024), dim3(256), 0, stream, Wv, bv, pA, ctx, nch);
    hipLaunchKernelGGL(k_pool, dim3(1024), dim3(256), 0, stream, Wo, bo, ctx, pooled);
    hipLaunchKernelGGL(k_head, dim3(64),   dim3(256), 0, stream, pooled, g2, b2, Wp, bp, out);
}

// Round 11
// 255.075 us; speedup vs baseline: 1.6794x; 1.1155x over previous
//
#include <hip/hip_runtime.h>
#include <hip/hip_bf16.h>

#define BB 64
#define DD 1024
#define HH 16
#define LL 4101          // 1 + 4 + 4096
#define NCH 8
#define CHUNK 513
#define SCALE 0.125f
#define LN_EPS 1e-5f

typedef float  f32x4 __attribute__((ext_vector_type(4)));
typedef short  s16x8 __attribute__((ext_vector_type(8)));
typedef unsigned int u32x4 __attribute__((ext_vector_type(4)));

// workspace layout (float offsets)
#define WS_QVEC 0               // 1024
#define WS_GU   1024            // 16*1024
#define WS_G    17408           // 16
#define WS_BU   17424           // 16
#define WS_CB   17440           // 16
#define WS_PL   17456           // 8192
#define WS_PM   25648           // 8192
#define WS_PA   33840           // 8388608
#define WS_CTX  8422448         // 65536
#define WS_POOL 8487984         // 65536

__device__ __forceinline__ unsigned int pk2(float a, float b) {
    __hip_bfloat162 h = __float22bfloat162_rn(make_float2(a, b));
    unsigned int r;
    __builtin_memcpy(&r, &h, 4);
    return r;
}

// ---------------- prep: qp = Wq*query + bq ----------------
__global__ void k_qvec(const float* __restrict__ query, const float* __restrict__ Wq,
                       const float* __restrict__ bq, float* __restrict__ qvec) {
    int j = blockIdx.x; int lane = threadIdx.x;          // 64 threads
    const float4* wr = reinterpret_cast<const float4*>(Wq + (size_t)j * DD);
    const float4* qr = reinterpret_cast<const float4*>(query);
    float s = 0.f;
#pragma unroll
    for (int k = 0; k < 4; ++k) {
        float4 a = wr[k * 64 + lane];
        float4 q = qr[k * 64 + lane];
        s += a.x * q.x + a.y * q.y + a.z * q.z + a.w * q.w;
    }
#pragma unroll
    for (int m = 1; m < 64; m <<= 1) s += __shfl_xor(s, m, 64);
    if (lane == 0) qvec[j] = s + bq[j];
}

// ---------------- prep: gu = g .* (scale*Wk_h^T qp_h), G_h, Bu_h ----------------
__global__ void k_u(const float* __restrict__ Wk, const float* __restrict__ qvec,
                    const float* __restrict__ g, const float* __restrict__ bln,
                    float* __restrict__ gu, float* __restrict__ Gv, float* __restrict__ Bu) {
    int h = blockIdx.x; int tid = threadIdx.x;
    int w = tid >> 6, lane = tid & 63;
    __shared__ float qs[64];
    __shared__ float red[8];
    if (tid < 64) qs[tid] = qvec[h * 64 + tid];
    __syncthreads();
    int d0 = tid * 4;
    float ax = 0.f, ay = 0.f, az = 0.f, aw = 0.f;
    for (int i = 0; i < 64; ++i) {
        float q = qs[i];
        float4 wv = *reinterpret_cast<const float4*>(&Wk[(size_t)(h * 64 + i) * DD + d0]);
        ax += q * wv.x; ay += q * wv.y; az += q * wv.z; aw += q * wv.w;
    }
    float4 g4 = *reinterpret_cast<const float4*>(&g[d0]);
    float4 b4 = *reinterpret_cast<const float4*>(&bln[d0]);
    float ux = ax * SCALE, uy = ay * SCALE, uz = az * SCALE, uw = aw * SCALE;
    float4 gu4 = make_float4(ux * g4.x, uy * g4.y, uz * g4.z, uw * g4.w);
    *reinterpret_cast<float4*>(&gu[(size_t)h * DD + d0]) = gu4;
    float Gp = gu4.x + gu4.y + gu4.z + gu4.w;
    float Bp = ux * b4.x + uy * b4.y + uz * b4.z + uw * b4.w;
#pragma unroll
    for (int m = 1; m < 64; m <<= 1) { Gp += __shfl_xor(Gp, m, 64); Bp += __shfl_xor(Bp, m, 64); }
    if (lane == 0) { red[2 * w] = Gp; red[2 * w + 1] = Bp; }
    __syncthreads();
    if (tid == 0) {
        Gv[h] = red[0] + red[2] + red[4] + red[6];
        Bu[h] = red[1] + red[3] + red[5] + red[7];
    }
}

// ---------------- prep: CB_h = Bu_h + scale*(qp_h . bk_h) ----------------
__global__ void k_cq(const float* __restrict__ qvec, const float* __restrict__ bk,
                     const float* __restrict__ Bu, float* __restrict__ CB) {
    int h = threadIdx.x;
    if (h < HH) {
        float s = 0.f;
        for (int i = 0; i < 64; ++i) s += qvec[h * 64 + i] * bk[h * 64 + i];
        CB[h] = Bu[h] + s * SCALE;
    }
}

// ---------------- fused main pass (R4 structure; stats via MFMA) ----------------
__global__ __launch_bounds__(256, 2) void k_main(
    const float* __restrict__ cls, const float* __restrict__ sto,
    const float* __restrict__ pat, const float* __restrict__ gu,
    const float* __restrict__ Gv, const float* __restrict__ CBv,
    float* __restrict__ pA, float* __restrict__ pl, float* __restrict__ pM) {

    __shared__ __align__(16) ushort Xlds[32 * 1024];   // 64 KB, subtiled [r>>2][d>>4][r&3][d&15]
    __shared__ __align__(16) f32x4 csr[4][2][64];      // 8 KB score partials
    __shared__ __align__(16) float sstat[2][32][4];    // 1 KB  [stat][row][wave]
    __shared__ __align__(16) ushort alds[512];         // 1 KB  alpha bf16 [16h][32r]
    __shared__ float2 mrs[32];                         // (rstd, -mean*rstd)

    const int blk = blockIdx.x;
    const int b = blk >> 3, ch = blk & 7;
    const int row0 = ch * CHUNK;
    const int rows = min(CHUNK, LL - row0);
    const int nt = (rows + 31) >> 5;
    const int tid = threadIdx.x;
    const int w = tid >> 6, lane = tid & 63;
    const int lm = lane & 15, lg = lane >> 4;

    // preload gu B-fragments: head=lm, d = w*256 + s*32 + lg*8 + j
    s16x8 guf[8];
    {
        const float* gubase = gu + (size_t)lm * DD + w * 256 + lg * 8;
#pragma unroll
        for (int s = 0; s < 8; ++s) {
            const float* p = gubase + s * 32;
            u32x4 t;
#pragma unroll
            for (int j = 0; j < 4; ++j) t[j] = pk2(p[2 * j], p[2 * j + 1]);
            s16x8 f; __builtin_memcpy(&f, &t, 16);
            guf[s] = f;
        }
    }
    s16x8 ones;
#pragma unroll
    for (int j = 0; j < 8; ++j) ones[j] = (short)0x3F80;  // bf16 1.0

    const float Gh = Gv[lm], CBh = CBv[lm];

    f32x4 acc[16];
#pragma unroll
    for (int i = 0; i < 16; ++i) acc[i] = (f32x4){0.f, 0.f, 0.f, 0.f};
    float lacc = 0.f, macc = 0.f;

    // per-lane constants (element indices into Xlds)
    const int C0 = (lm >> 2) * 4096 + w * 1024 + (lg >> 1) * 64 + (lm & 3) * 16 + (lg & 1) * 8;
    const int bbase = lg * 8192 + w * 1024 + lm;   // op4 B-frag base: r=8lg, d=w*256+lm
    const int aoff = lm * 32 + lg * 8;

    for (int t = 0; t < nt; ++t) {
        // ---- stage: fp32->bf16 into subtiled Xlds (no stats here) ----
#pragma unroll 2
        for (int rr = 0; rr < 8; ++rr) {
            int rl = w * 8 + rr;
            int rloc = t * 32 + rl;
            bool valid = rloc < rows;
            float4 v[4];
            if (valid) {
                int gr = row0 + rloc;
                const float* src;
                if (gr == 0)      src = cls + (size_t)b * DD;
                else if (gr <= 4) src = sto + ((size_t)b * 4 + (gr - 1)) * DD;
                else              src = pat + ((size_t)b * 4096 + (gr - 5)) * DD;
                const float4* s4 = reinterpret_cast<const float4*>(src);
#pragma unroll
                for (int it = 0; it < 4; ++it) v[it] = s4[it * 64 + lane];
            } else {
#pragma unroll
                for (int it = 0; it < 4; ++it) v[it] = make_float4(0.f, 0.f, 0.f, 0.f);
            }
#pragma unroll
            for (int it = 0; it < 4; ++it) {
                uint2 pk;
                pk.x = pk2(v[it].x, v[it].y);
                pk.y = pk2(v[it].z, v[it].w);
                int d0 = 4 * (it * 64 + lane);
                int elem = ((rl >> 2) * 64 + (d0 >> 4)) * 64 + ((rl & 3) << 4) + (d0 & 15);
                *reinterpret_cast<uint2*>(&Xlds[elem]) = pk;
            }
        }
        __syncthreads();

        // ---- op2: score dot partials + LN stats via MFMA ----
        {
            f32x4 c0 = {0.f,0.f,0.f,0.f}, c1 = {0.f,0.f,0.f,0.f};
            f32x4 q0 = {0.f,0.f,0.f,0.f}, q1 = {0.f,0.f,0.f,0.f};
            f32x4 m0 = {0.f,0.f,0.f,0.f}, m1 = {0.f,0.f,0.f,0.f};
#pragma unroll
            for (int s = 0; s < 8; ++s) {
                s16x8 a0 = *reinterpret_cast<const s16x8*>(&Xlds[C0 + s * 128]);
                s16x8 a1 = *reinterpret_cast<const s16x8*>(&Xlds[C0 + 16384 + s * 128]);
                c0 = __builtin_amdgcn_mfma_f32_16x16x32_bf16(a0, guf[s], c0, 0, 0, 0);
                c1 = __builtin_amdgcn_mfma_f32_16x16x32_bf16(a1, guf[s], c1, 0, 0, 0);
                q0 = __builtin_amdgcn_mfma_f32_16x16x32_bf16(a0, a0,     q0, 0, 0, 0);
                q1 = __builtin_amdgcn_mfma_f32_16x16x32_bf16(a1, a1,     q1, 0, 0, 0);
                m0 = __builtin_amdgcn_mfma_f32_16x16x32_bf16(a0, ones,   m0, 0, 0, 0);
                m1 = __builtin_amdgcn_mfma_f32_16x16x32_bf16(a1, ones,   m1, 0, 0, 0);
            }
            csr[w][0][lane] = c0;
            csr[w][1][lane] = c1;
            if (lg == (lm >> 2)) {                  // diag holders: row==col==lm
                sstat[0][lm][w]      = q0[lm & 3];
                sstat[0][16 + lm][w] = q1[lm & 3];
            }
            if (lm == 0) {                          // col 0 holds row sums
#pragma unroll
                for (int i = 0; i < 4; ++i) {
                    sstat[1][lg * 4 + i][w]      = m0[i];
                    sstat[1][16 + lg * 4 + i][w] = m1[i];
                }
            }
        }
        __syncthreads();

        // ---- finalize (wave 0 only) ----
        if (w == 0) {
            if (lane < 32) {
                f32x4 qv = *reinterpret_cast<const f32x4*>(&sstat[0][lane][0]);
                f32x4 mv = *reinterpret_cast<const f32x4*>(&sstat[1][lane][0]);
                float s2 = qv[0] + qv[1] + qv[2] + qv[3];
                float s1 = mv[0] + mv[1] + mv[2] + mv[3];
                float mean = s1 * (1.f / 1024.f);
                float var  = s2 * (1.f / 1024.f) - mean * mean;
                float rstd = rsqrtf(var + LN_EPS);
                mrs[lane] = make_float2(rstd, -mean * rstd);
            }
            asm volatile("s_waitcnt lgkmcnt(0)" ::: "memory");   // in-wave mrs visibility
            __builtin_amdgcn_sched_barrier(0);
            f32x4 d0v = csr[0][0][lane], d1v = csr[0][1][lane];
#pragma unroll
            for (int wp = 1; wp < 4; ++wp) {
                f32x4 e0 = csr[wp][0][lane], e1 = csr[wp][1][lane];
                d0v += e0; d1v += e1;
            }
#pragma unroll
            for (int tt = 0; tt < 2; ++tt) {
                f32x4 dv = tt ? d1v : d0v;
                int rbase = tt * 16 + lg * 4;
                float al[4];
#pragma unroll
                for (int i = 0; i < 4; ++i) {
                    float2 mr = mrs[rbase + i];
                    float sc = dv[i] * mr.x + (mr.y * Gh + CBh);
                    bool vld = (t * 32 + rbase + i) < rows;
                    float p = vld ? __expf(sc) : 0.f;
                    lacc += p;
                    macc += p * mr.y;          // = -sum(p*mean*rstd)
                    al[i] = p * mr.x;          // alpha
                }
                unsigned int qq0 = pk2(al[0], al[1]);
                unsigned int qq1 = pk2(al[2], al[3]);
                *reinterpret_cast<unsigned int*>(&alds[lm * 32 + rbase])     = qq0;
                *reinterpret_cast<unsigned int*>(&alds[lm * 32 + rbase + 2]) = qq1;
            }
        }
        __syncthreads();

        // ---- op4: acc[h][d] += alpha^T . X  (B-frags via scalar LDS reads) ----
        {
            s16x8 af = *reinterpret_cast<const s16x8*>(&alds[aoff]);
#pragma unroll
            for (int dt = 0; dt < 16; ++dt) {
                s16x8 bfrag;
#pragma unroll
                for (int j = 0; j < 8; ++j) {
                    // r = 8*lg + j, d = w*256 + dt*16 + lm
                    int e = bbase + dt * 64 + ((j & 3) << 4) + ((j >> 2) << 12);
                    bfrag[j] = (short)Xlds[e];
                }
                acc[dt] = __builtin_amdgcn_mfma_f32_16x16x32_bf16(af, bfrag, acc[dt], 0, 0, 0);
            }
        }
        __syncthreads();
    }

    // write partial A  (pA[blk][h][1024])
    size_t pabase = ((size_t)blk << 14);
#pragma unroll
    for (int dt = 0; dt < 16; ++dt) {
#pragma unroll
        for (int i = 0; i < 4; ++i) {
            int h = lg * 4 + i;
            pA[pabase + ((size_t)h << 10) + w * 256 + dt * 16 + lm] = acc[dt][i];
        }
    }
    if (w == 0) {
        lacc += __shfl_xor(lacc, 16, 64); lacc += __shfl_xor(lacc, 32, 64);
        macc += __shfl_xor(macc, 16, 64); macc += __shfl_xor(macc, 32, 64);
        if (lane < 16) {
            pl[blk * 16 + lane] = lacc;
            pM[blk * 16 + lane] = -macc;       // = sum(p*mean*rstd)
        }
    }
}

// ---------------- combine partials: sbar = (g.*(A - M))/l + b  (overlays pA ch=0) ----------------
__global__ void k_comb(float* __restrict__ pA, const float* __restrict__ pl,
                       const float* __restrict__ pM, const float* __restrict__ g,
                       const float* __restrict__ bln) {
    int blk = blockIdx.x; int b = blk >> 4; int h = blk & 15; int tid = threadIdx.x;
    float l = 0.f, M = 0.f;
#pragma unroll
    for (int ch = 0; ch < NCH; ++ch) {
        l += pl[(b * NCH + ch) * 16 + h];
        M += pM[(b * NCH + ch) * 16 + h];
    }
    float inv = 1.f / l;
    float4 s = make_float4(0.f, 0.f, 0.f, 0.f);
#pragma unroll
    for (int ch = 0; ch < NCH; ++ch) {
        const float4* p4 = reinterpret_cast<const float4*>(
            pA + (((size_t)(b * NCH + ch) * 16 + h) << 10));
        float4 v = p4[tid];
        s.x += v.x; s.y += v.y; s.z += v.z; s.w += v.w;
    }
    float4 g4 = *reinterpret_cast<const float4*>(&g[tid * 4]);
    float4 b4 = *reinterpret_cast<const float4*>(&bln[tid * 4]);
    float4 o;
    o.x = g4.x * (s.x - M) * inv + b4.x;
    o.y = g4.y * (s.y - M) * inv + b4.y;
    o.z = g4.z * (s.z - M) * inv + b4.z;
    o.w = g4.w * (s.w - M) * inv + b4.w;
    float4* dst = reinterpret_cast<float4*>(pA + (((size_t)(b * NCH) * 16 + h) << 10));
    dst[tid] = o;
}

// ---------------- ctx = Wv_h * sbar_h + bv ----------------
__global__ void k_ctx(const float* __restrict__ Wv, const float* __restrict__ bv,
                      const float* __restrict__ pA, float* __restrict__ ctx) {
    int j = blockIdx.x; int h = j >> 6;
    int w = threadIdx.x >> 6, lane = threadIdx.x & 63;
    const float4* wr = reinterpret_cast<const float4*>(Wv + (size_t)j * DD);
    float4 wv[4];
#pragma unroll
    for (int k = 0; k < 4; ++k) wv[k] = wr[k * 64 + lane];
    float bvj = bv[j];
    for (int bb2 = w * 16; bb2 < w * 16 + 16; ++bb2) {
        const float4* sr = reinterpret_cast<const float4*>(
            pA + (((size_t)(bb2 * NCH) * 16 + h) << 10));
        float s = 0.f;
#pragma unroll
        for (int k = 0; k < 4; ++k) {
            float4 v = sr[k * 64 + lane];
            s += wv[k].x * v.x + wv[k].y * v.y + wv[k].z * v.z + wv[k].w * v.w;
        }
#pragma unroll
        for (int m = 1; m < 64; m <<= 1) s += __shfl_xor(s, m, 64);
        if (lane == 0) ctx[(size_t)bb2 * DD + j] = s + bvj;
    }
}

// ---------------- pooled = Wo * ctx + bo ----------------
__global__ void k_pool(const float* __restrict__ Wo, const float* __restrict__ bo,
                       const float* __restrict__ ctx, float* __restrict__ pooled) {
    int j = blockIdx.x;
    int w = threadIdx.x >> 6, lane = threadIdx.x & 63;
    const float4* wr = reinterpret_cast<const float4*>(Wo + (size_t)j * DD);
    float4 wv[4];
#pragma unroll
    for (int k = 0; k < 4; ++k) wv[k] = wr[k * 64 + lane];
    float boj = bo[j];
    for (int bb2 = w * 16; bb2 < w * 16 + 16; ++bb2) {
        const float4* cr4 = reinterpret_cast<const float4*>(ctx + (size_t)bb2 * DD);
        float s = 0.f;
#pragma unroll
        for (int k = 0; k < 4; ++k) {
            float4 v = cr4[k * 64 + lane];
            s += wv[k].x * v.x + wv[k].y * v.y + wv[k].z * v.z + wv[k].w * v.w;
        }
#pragma unroll
        for (int m = 1; m < 64; m <<= 1) s += __shfl_xor(s, m, 64);
        if (lane == 0) pooled[(size_t)bb2 * DD + j] = s + boj;
    }
}

// ---------------- final LN + classifier head ----------------
__global__ void k_head(const float* __restrict__ pooled, const float* __restrict__ g2,
                       const float* __restrict__ b2, const float* __restrict__ Wp,
                       const float* __restrict__ bp, float* __restrict__ out) {
    int b = blockIdx.x; int tid = threadIdx.x;
    __shared__ float pln[DD];
    __shared__ float red[8];
    const float4* pr = reinterpret_cast<const float4*>(pooled + (size_t)b * DD);
    float4 v = pr[tid];
    float s1 = v.x + v.y + v.z + v.w;
    float s2 = v.x * v.x + v.y * v.y + v.z * v.z + v.w * v.w;
#pragma unroll
    for (int m = 1; m < 64; m <<= 1) { s1 += __shfl_xor(s1, m, 64); s2 += __shfl_xor(s2, m, 64); }
    int w = tid >> 6, lane = tid & 63;
    if (lane == 0) { red[2 * w] = s1; red[2 * w + 1] = s2; }
    __syncthreads();
    s1 = red[0] + red[2] + red[4] + red[6];
    s2 = red[1] + red[3] + red[5] + red[7];
    float mean = s1 * (1.f / 1024.f);
    float var  = s2 * (1.f / 1024.f) - mean * mean;
    float rstd = rsqrtf(var + LN_EPS);
    int d0 = tid * 4;
    pln[d0 + 0] = (v.x - mean) * rstd * g2[d0 + 0] + b2[d0 + 0];
    pln[d0 + 1] = (v.y - mean) * rstd * g2[d0 + 1] + b2[d0 + 1];
    pln[d0 + 2] = (v.z - mean) * rstd * g2[d0 + 2] + b2[d0 + 2];
    pln[d0 + 3] = (v.w - mean) * rstd * g2[d0 + 3] + b2[d0 + 3];
    __syncthreads();
    int q = tid & 15, c = tid >> 4;
    if (c < 14) {
        float s = 0.f;
#pragma unroll 8
        for (int i = 0; i < 64; ++i) {
            int d = i * 16 + q;
            s += pln[d] * Wp[c * DD + d];
        }
#pragma unroll
        for (int m = 1; m < 16; m <<= 1) s += __shfl_xor(s, m, 64);
        if (q == 0) out[b * 14 + c] = s + bp[c];
    }
}

extern "C" void kernel_launch(void* const* d_in, const int* in_sizes, int n_in,
                              void* d_out, int out_size, void* d_ws, size_t ws_size,
                              hipStream_t stream) {
    const float* cls   = (const float*)d_in[0];
    const float* sto   = (const float*)d_in[1];
    const float* pat   = (const float*)d_in[2];
    const float* query = (const float*)d_in[3];
    const float* g     = (const float*)d_in[4];
    const float* bln   = (const float*)d_in[5];
    const float* Wq    = (const float*)d_in[6];
    const float* Wk    = (const float*)d_in[7];
    const float* Wv    = (const float*)d_in[8];
    const float* bq    = (const float*)d_in[9];
    const float* bk    = (const float*)d_in[10];
    const float* bv    = (const float*)d_in[11];
    const float* Wo    = (const float*)d_in[12];
    const float* bo    = (const float*)d_in[13];
    const float* g2    = (const float*)d_in[14];
    const float* b2    = (const float*)d_in[15];
    const float* Wp    = (const float*)d_in[16];
    const float* bp    = (const float*)d_in[17];

    float* ws     = (float*)d_ws;
    float* qvec   = ws + WS_QVEC;
    float* gu     = ws + WS_GU;
    float* Gv     = ws + WS_G;
    float* Bu     = ws + WS_BU;
    float* CB     = ws + WS_CB;
    float* pl     = ws + WS_PL;
    float* pM     = ws + WS_PM;
    float* pA     = ws + WS_PA;
    float* ctx    = ws + WS_CTX;
    float* pooled = ws + WS_POOL;
    float* out    = (float*)d_out;

    hipLaunchKernelGGL(k_qvec, dim3(1024), dim3(64), 0, stream, query, Wq, bq, qvec);
    hipLaunchKernelGGL(k_u,    dim3(16),   dim3(256), 0, stream, Wk, qvec, g, bln, gu, Gv, Bu);
    hipLaunchKernelGGL(k_cq,   dim3(1),    dim3(64), 0, stream, qvec, bk, Bu, CB);
    hipLaunchKernelGGL(k_main, dim3(BB * NCH), dim3(256), 0, stream,
                       cls, sto, pat, gu, Gv, CB, pA, pl, pM);
    hipLaunchKernelGGL(k_comb, dim3(BB * HH), dim3(256), 0, stream, pA, pl, pM, g, bln);
    hipLaunchKernelGGL(k_ctx,  dim3(1024), dim3(256), 0, stream, Wv, bv, pA, ctx);
    hipLaunchKernelGGL(k_pool, dim3(1024), dim3(256), 0, stream, Wo, bo, ctx, pooled);
    hipLaunchKernelGGL(k_head, dim3(64),   dim3(256), 0, stream, pooled, g2, b2, Wp, bp, out);
}

// Round 12
// 254.691 us; speedup vs baseline: 1.6819x; 1.0015x over previous
//
#include <hip/hip_runtime.h>
#include <hip/hip_bf16.h>

#define BB 64
#define DD 1024
#define HH 16
#define LL 4101          // 1 + 4 + 4096
#define NCH 8
#define CHUNK 513
#define SCALE 0.125f
#define LN_EPS 1e-5f
#define RGS 4112         // padded row-group stride (elem): 2056 dw = 8 mod 32 -> conflict-lite

typedef float  f32x4 __attribute__((ext_vector_type(4)));
typedef short  s16x8 __attribute__((ext_vector_type(8)));
typedef unsigned int u32x4 __attribute__((ext_vector_type(4)));

// workspace layout (float offsets)
#define WS_QVEC 0               // 1024
#define WS_GU   1024            // 16*1024
#define WS_G    17408           // 16
#define WS_BU   17424           // 16
#define WS_CB   17440           // 16
#define WS_PL   17456           // 8192
#define WS_PM   25648           // 8192
#define WS_PA   33840           // 8388608
#define WS_CTX  8422448         // 65536
#define WS_POOL 8487984         // 65536

__device__ __forceinline__ unsigned int pk2(float a, float b) {
    __hip_bfloat162 h = __float22bfloat162_rn(make_float2(a, b));
    unsigned int r;
    __builtin_memcpy(&r, &h, 4);
    return r;
}

// ---------------- prep: qp = Wq*query + bq ----------------
__global__ void k_qvec(const float* __restrict__ query, const float* __restrict__ Wq,
                       const float* __restrict__ bq, float* __restrict__ qvec) {
    int j = blockIdx.x; int lane = threadIdx.x;          // 64 threads
    const float4* wr = reinterpret_cast<const float4*>(Wq + (size_t)j * DD);
    const float4* qr = reinterpret_cast<const float4*>(query);
    float s = 0.f;
#pragma unroll
    for (int k = 0; k < 4; ++k) {
        float4 a = wr[k * 64 + lane];
        float4 q = qr[k * 64 + lane];
        s += a.x * q.x + a.y * q.y + a.z * q.z + a.w * q.w;
    }
#pragma unroll
    for (int m = 1; m < 64; m <<= 1) s += __shfl_xor(s, m, 64);
    if (lane == 0) qvec[j] = s + bq[j];
}

// ---------------- prep: gu = g .* (scale*Wk_h^T qp_h), G_h, Bu_h ----------------
__global__ void k_u(const float* __restrict__ Wk, const float* __restrict__ qvec,
                    const float* __restrict__ g, const float* __restrict__ bln,
                    float* __restrict__ gu, float* __restrict__ Gv, float* __restrict__ Bu) {
    int h = blockIdx.x; int tid = threadIdx.x;
    int w = tid >> 6, lane = tid & 63;
    __shared__ float qs[64];
    __shared__ float red[8];
    if (tid < 64) qs[tid] = qvec[h * 64 + tid];
    __syncthreads();
    int d0 = tid * 4;
    float ax = 0.f, ay = 0.f, az = 0.f, aw = 0.f;
    for (int i = 0; i < 64; ++i) {
        float q = qs[i];
        float4 wv = *reinterpret_cast<const float4*>(&Wk[(size_t)(h * 64 + i) * DD + d0]);
        ax += q * wv.x; ay += q * wv.y; az += q * wv.z; aw += q * wv.w;
    }
    float4 g4 = *reinterpret_cast<const float4*>(&g[d0]);
    float4 b4 = *reinterpret_cast<const float4*>(&bln[d0]);
    float ux = ax * SCALE, uy = ay * SCALE, uz = az * SCALE, uw = aw * SCALE;
    float4 gu4 = make_float4(ux * g4.x, uy * g4.y, uz * g4.z, uw * g4.w);
    *reinterpret_cast<float4*>(&gu[(size_t)h * DD + d0]) = gu4;
    float Gp = gu4.x + gu4.y + gu4.z + gu4.w;
    float Bp = ux * b4.x + uy * b4.y + uz * b4.z + uw * b4.w;
#pragma unroll
    for (int m = 1; m < 64; m <<= 1) { Gp += __shfl_xor(Gp, m, 64); Bp += __shfl_xor(Bp, m, 64); }
    if (lane == 0) { red[2 * w] = Gp; red[2 * w + 1] = Bp; }
    __syncthreads();
    if (tid == 0) {
        Gv[h] = red[0] + red[2] + red[4] + red[6];
        Bu[h] = red[1] + red[3] + red[5] + red[7];
    }
}

// ---------------- prep: CB_h = Bu_h + scale*(qp_h . bk_h) ----------------
__global__ void k_cq(const float* __restrict__ qvec, const float* __restrict__ bk,
                     const float* __restrict__ Bu, float* __restrict__ CB) {
    int h = threadIdx.x;
    if (h < HH) {
        float s = 0.f;
        for (int i = 0; i < 64; ++i) s += qvec[h * 64 + i] * bk[h * 64 + i];
        CB[h] = Bu[h] + s * SCALE;
    }
}

// ---------------- fused main pass (MFMA stats + padded LDS + all-wave finalize) ----------------
__global__ __launch_bounds__(256, 2) void k_main(
    const float* __restrict__ cls, const float* __restrict__ sto,
    const float* __restrict__ pat, const float* __restrict__ gu,
    const float* __restrict__ Gv, const float* __restrict__ CBv,
    float* __restrict__ pA, float* __restrict__ pl, float* __restrict__ pM) {

    __shared__ __align__(16) ushort Xlds[8 * RGS];     // 65,792 B padded subtiled
    __shared__ __align__(16) f32x4 csr[4][2][64];      // 8 KB score partials
    __shared__ __align__(16) float sstat[2][32][4];    // 1 KB [stat][row][wave]
    __shared__ __align__(16) ushort alds[512];         // 1 KB alpha bf16 [16h][32r]
    __shared__ float2 mrs[32];                         // (rstd, -mean*rstd)

    const int blk = blockIdx.x;
    const int b = blk >> 3, ch = blk & 7;
    const int row0 = ch * CHUNK;
    const int rows = min(CHUNK, LL - row0);
    const int nt = (rows + 31) >> 5;
    const int tid = threadIdx.x;
    const int w = tid >> 6, lane = tid & 63;
    const int lm = lane & 15, lg = lane >> 4;

    // preload gu B-fragments: head=lm, d = w*256 + s*32 + lg*8 + j
    s16x8 guf[8];
    {
        const float* gubase = gu + (size_t)lm * DD + w * 256 + lg * 8;
#pragma unroll
        for (int s = 0; s < 8; ++s) {
            const float* p = gubase + s * 32;
            u32x4 t;
#pragma unroll
            for (int j = 0; j < 4; ++j) t[j] = pk2(p[2 * j], p[2 * j + 1]);
            s16x8 f; __builtin_memcpy(&f, &t, 16);
            guf[s] = f;
        }
    }
    s16x8 ones;
#pragma unroll
    for (int j = 0; j < 8; ++j) ones[j] = (short)0x3F80;  // bf16 1.0

    const float Gh = Gv[lm], CBh = CBv[lm];

    f32x4 acc[16];
#pragma unroll
    for (int i = 0; i < 16; ++i) acc[i] = (f32x4){0.f, 0.f, 0.f, 0.f};
    float lacc = 0.f, macc = 0.f;

    // per-lane constants (element indices into Xlds)
    const int C0 = (lm >> 2) * RGS + w * 1024 + (lg >> 1) * 64 + (lm & 3) * 16 + (lg & 1) * 8;
    const int A1O = 4 * RGS;
    const int bbase = lg * 2 * RGS + w * 1024 + lm;   // op4 B-frag base: r=8lg, d=w*256+lm
    const int aoff = lm * 32 + lg * 8;

    for (int t = 0; t < nt; ++t) {
        // ---- stage: fp32->bf16 into subtiled Xlds ----
#pragma unroll 2
        for (int rr = 0; rr < 8; ++rr) {
            int rl = w * 8 + rr;
            int rloc = t * 32 + rl;
            bool valid = rloc < rows;
            float4 v[4];
            if (valid) {
                int gr = row0 + rloc;
                const float* src;
                if (gr == 0)      src = cls + (size_t)b * DD;
                else if (gr <= 4) src = sto + ((size_t)b * 4 + (gr - 1)) * DD;
                else              src = pat + ((size_t)b * 4096 + (gr - 5)) * DD;
                const float4* s4 = reinterpret_cast<const float4*>(src);
#pragma unroll
                for (int it = 0; it < 4; ++it) v[it] = s4[it * 64 + lane];
            } else {
#pragma unroll
                for (int it = 0; it < 4; ++it) v[it] = make_float4(0.f, 0.f, 0.f, 0.f);
            }
#pragma unroll
            for (int it = 0; it < 4; ++it) {
                uint2 pk;
                pk.x = pk2(v[it].x, v[it].y);
                pk.y = pk2(v[it].z, v[it].w);
                int d0 = 4 * (it * 64 + lane);
                int elem = (rl >> 2) * RGS + (d0 >> 4) * 64 + ((rl & 3) << 4) + (d0 & 15);
                *reinterpret_cast<uint2*>(&Xlds[elem]) = pk;
            }
        }
        __syncthreads();                                 // B1

        // ---- op2: score dot partials + LN stats via MFMA ----
        {
            f32x4 c0 = {0.f,0.f,0.f,0.f}, c1 = {0.f,0.f,0.f,0.f};
            f32x4 q0 = {0.f,0.f,0.f,0.f}, q1 = {0.f,0.f,0.f,0.f};
            f32x4 m0 = {0.f,0.f,0.f,0.f}, m1 = {0.f,0.f,0.f,0.f};
#pragma unroll
            for (int s = 0; s < 8; ++s) {
                s16x8 a0 = *reinterpret_cast<const s16x8*>(&Xlds[C0 + s * 128]);
                s16x8 a1 = *reinterpret_cast<const s16x8*>(&Xlds[C0 + A1O + s * 128]);
                c0 = __builtin_amdgcn_mfma_f32_16x16x32_bf16(a0, guf[s], c0, 0, 0, 0);
                c1 = __builtin_amdgcn_mfma_f32_16x16x32_bf16(a1, guf[s], c1, 0, 0, 0);
                q0 = __builtin_amdgcn_mfma_f32_16x16x32_bf16(a0, a0,     q0, 0, 0, 0);
                q1 = __builtin_amdgcn_mfma_f32_16x16x32_bf16(a1, a1,     q1, 0, 0, 0);
                m0 = __builtin_amdgcn_mfma_f32_16x16x32_bf16(a0, ones,   m0, 0, 0, 0);
                m1 = __builtin_amdgcn_mfma_f32_16x16x32_bf16(a1, ones,   m1, 0, 0, 0);
            }
            csr[w][0][lane] = c0;
            csr[w][1][lane] = c1;
            if (lg == (lm >> 2)) {                  // diag holders: row==col==lm
                sstat[0][lm][w]      = q0[lm & 3];
                sstat[0][16 + lm][w] = q1[lm & 3];
            }
            if (lm == 0) {                          // col 0 holds row sums
#pragma unroll
                for (int i = 0; i < 4; ++i) {
                    sstat[1][lg * 4 + i][w]      = m0[i];
                    sstat[1][16 + lg * 4 + i][w] = m1[i];
                }
            }
        }
        __syncthreads();                                 // B2 (csr/sstat cross-wave)

        // ---- finalize: all 4 waves redundantly (no extra barrier) ----
        if (lane < 32) {
            f32x4 qv = *reinterpret_cast<const f32x4*>(&sstat[0][lane][0]);
            f32x4 mv = *reinterpret_cast<const f32x4*>(&sstat[1][lane][0]);
            float s2 = qv[0] + qv[1] + qv[2] + qv[3];
            float s1 = mv[0] + mv[1] + mv[2] + mv[3];
            float mean = s1 * (1.f / 1024.f);
            float var  = s2 * (1.f / 1024.f) - mean * mean;
            float rstd = rsqrtf(var + LN_EPS);
            mrs[lane] = make_float2(rstd, -mean * rstd);
        }
        asm volatile("s_waitcnt lgkmcnt(0)" ::: "memory");   // in-wave mrs visibility
        __builtin_amdgcn_sched_barrier(0);
        {
            f32x4 d0v = csr[0][0][lane], d1v = csr[0][1][lane];
#pragma unroll
            for (int wp = 1; wp < 4; ++wp) {
                f32x4 e0 = csr[wp][0][lane], e1 = csr[wp][1][lane];
                d0v += e0; d1v += e1;
            }
#pragma unroll
            for (int tt = 0; tt < 2; ++tt) {
                f32x4 dv = tt ? d1v : d0v;
                int rbase = tt * 16 + lg * 4;
                float al[4];
#pragma unroll
                for (int i = 0; i < 4; ++i) {
                    float2 mr = mrs[rbase + i];
                    float sc = dv[i] * mr.x + (mr.y * Gh + CBh);
                    bool vld = (t * 32 + rbase + i) < rows;
                    float p = vld ? __expf(sc) : 0.f;
                    lacc += p;
                    macc += p * mr.y;          // = -sum(p*mean*rstd)
                    al[i] = p * mr.x;          // alpha
                }
                unsigned int qq0 = pk2(al[0], al[1]);
                unsigned int qq1 = pk2(al[2], al[3]);
                *reinterpret_cast<unsigned int*>(&alds[lm * 32 + rbase])     = qq0;
                *reinterpret_cast<unsigned int*>(&alds[lm * 32 + rbase + 2]) = qq1;
            }
        }
        asm volatile("s_waitcnt lgkmcnt(0)" ::: "memory");   // in-wave alds visibility
        __builtin_amdgcn_sched_barrier(0);

        // ---- op4: acc[h][d] += alpha^T . X  (B-frags via scalar LDS reads) ----
        {
            s16x8 af = *reinterpret_cast<const s16x8*>(&alds[aoff]);
#pragma unroll
            for (int dt = 0; dt < 16; ++dt) {
                s16x8 bfrag;
#pragma unroll
                for (int j = 0; j < 8; ++j) {
                    // r = 8*lg + j, d = w*256 + dt*16 + lm
                    int e = bbase + dt * 64 + ((j & 3) << 4) + (j >> 2) * RGS;
                    bfrag[j] = (short)Xlds[e];
                }
                acc[dt] = __builtin_amdgcn_mfma_f32_16x16x32_bf16(af, bfrag, acc[dt], 0, 0, 0);
            }
        }
        __syncthreads();                                 // B3 (protect Xlds + alds)
    }

    // write partial A  (pA[blk][h][1024])
    size_t pabase = ((size_t)blk << 14);
#pragma unroll
    for (int dt = 0; dt < 16; ++dt) {
#pragma unroll
        for (int i = 0; i < 4; ++i) {
            int h = lg * 4 + i;
            pA[pabase + ((size_t)h << 10) + w * 256 + dt * 16 + lm] = acc[dt][i];
        }
    }
    if (w == 0) {
        lacc += __shfl_xor(lacc, 16, 64); lacc += __shfl_xor(lacc, 32, 64);
        macc += __shfl_xor(macc, 16, 64); macc += __shfl_xor(macc, 32, 64);
        if (lane < 16) {
            pl[blk * 16 + lane] = lacc;
            pM[blk * 16 + lane] = -macc;       // = sum(p*mean*rstd)
        }
    }
}

// ---------------- combine partials: sbar = (g.*(A - M))/l + b  (overlays pA ch=0) ----------------
__global__ void k_comb(float* __restrict__ pA, const float* __restrict__ pl,
                       const float* __restrict__ pM, const float* __restrict__ g,
                       const float* __restrict__ bln) {
    int blk = blockIdx.x; int b = blk >> 4; int h = blk & 15; int tid = threadIdx.x;
    float l = 0.f, M = 0.f;
#pragma unroll
    for (int ch = 0; ch < NCH; ++ch) {
        l += pl[(b * NCH + ch) * 16 + h];
        M += pM[(b * NCH + ch) * 16 + h];
    }
    float inv = 1.f / l;
    float4 s = make_float4(0.f, 0.f, 0.f, 0.f);
#pragma unroll
    for (int ch = 0; ch < NCH; ++ch) {
        const float4* p4 = reinterpret_cast<const float4*>(
            pA + (((size_t)(b * NCH + ch) * 16 + h) << 10));
        float4 v = p4[tid];
        s.x += v.x; s.y += v.y; s.z += v.z; s.w += v.w;
    }
    float4 g4 = *reinterpret_cast<const float4*>(&g[tid * 4]);
    float4 b4 = *reinterpret_cast<const float4*>(&bln[tid * 4]);
    float4 o;
    o.x = g4.x * (s.x - M) * inv + b4.x;
    o.y = g4.y * (s.y - M) * inv + b4.y;
    o.z = g4.z * (s.z - M) * inv + b4.z;
    o.w = g4.w * (s.w - M) * inv + b4.w;
    float4* dst = reinterpret_cast<float4*>(pA + (((size_t)(b * NCH) * 16 + h) << 10));
    dst[tid] = o;
}

// ---------------- ctx = Wv_h * sbar_h + bv ----------------
__global__ void k_ctx(const float* __restrict__ Wv, const float* __restrict__ bv,
                      const float* __restrict__ pA, float* __restrict__ ctx) {
    int j = blockIdx.x; int h = j >> 6;
    int w = threadIdx.x >> 6, lane = threadIdx.x & 63;
    const float4* wr = reinterpret_cast<const float4*>(Wv + (size_t)j * DD);
    float4 wv[4];
#pragma unroll
    for (int k = 0; k < 4; ++k) wv[k] = wr[k * 64 + lane];
    float bvj = bv[j];
    for (int bb2 = w * 16; bb2 < w * 16 + 16; ++bb2) {
        const float4* sr = reinterpret_cast<const float4*>(
            pA + (((size_t)(bb2 * NCH) * 16 + h) << 10));
        float s = 0.f;
#pragma unroll
        for (int k = 0; k < 4; ++k) {
            float4 v = sr[k * 64 + lane];
            s += wv[k].x * v.x + wv[k].y * v.y + wv[k].z * v.z + wv[k].w * v.w;
        }
#pragma unroll
        for (int m = 1; m < 64; m <<= 1) s += __shfl_xor(s, m, 64);
        if (lane == 0) ctx[(size_t)bb2 * DD + j] = s + bvj;
    }
}

// ---------------- pooled = Wo * ctx + bo ----------------
__global__ void k_pool(const float* __restrict__ Wo, const float* __restrict__ bo,
                       const float* __restrict__ ctx, float* __restrict__ pooled) {
    int j = blockIdx.x;
    int w = threadIdx.x >> 6, lane = threadIdx.x & 63;
    const float4* wr = reinterpret_cast<const float4*>(Wo + (size_t)j * DD);
    float4 wv[4];
#pragma unroll
    for (int k = 0; k < 4; ++k) wv[k] = wr[k * 64 + lane];
    float boj = bo[j];
    for (int bb2 = w * 16; bb2 < w * 16 + 16; ++bb2) {
        const float4* cr4 = reinterpret_cast<const float4*>(ctx + (size_t)bb2 * DD);
        float s = 0.f;
#pragma unroll
        for (int k = 0; k < 4; ++k) {
            float4 v = cr4[k * 64 + lane];
            s += wv[k].x * v.x + wv[k].y * v.y + wv[k].z * v.z + wv[k].w * v.w;
        }
#pragma unroll
        for (int m = 1; m < 64; m <<= 1) s += __shfl_xor(s, m, 64);
        if (lane == 0) pooled[(size_t)bb2 * DD + j] = s + boj;
    }
}

// ---------------- final LN + classifier head ----------------
__global__ void k_head(const float* __restrict__ pooled, const float* __restrict__ g2,
                       const float* __restrict__ b2, const float* __restrict__ Wp,
                       const float* __restrict__ bp, float* __restrict__ out) {
    int b = blockIdx.x; int tid = threadIdx.x;
    __shared__ float pln[DD];
    __shared__ float red[8];
    const float4* pr = reinterpret_cast<const float4*>(pooled + (size_t)b * DD);
    float4 v = pr[tid];
    float s1 = v.x + v.y + v.z + v.w;
    float s2 = v.x * v.x + v.y * v.y + v.z * v.z + v.w * v.w;
#pragma unroll
    for (int m = 1; m < 64; m <<= 1) { s1 += __shfl_xor(s1, m, 64); s2 += __shfl_xor(s2, m, 64); }
    int w = tid >> 6, lane = tid & 63;
    if (lane == 0) { red[2 * w] = s1; red[2 * w + 1] = s2; }
    __syncthreads();
    s1 = red[0] + red[2] + red[4] + red[6];
    s2 = red[1] + red[3] + red[5] + red[7];
    float mean = s1 * (1.f / 1024.f);
    float var  = s2 * (1.f / 1024.f) - mean * mean;
    float rstd = rsqrtf(var + LN_EPS);
    int d0 = tid * 4;
    pln[d0 + 0] = (v.x - mean) * rstd * g2[d0 + 0] + b2[d0 + 0];
    pln[d0 + 1] = (v.y - mean) * rstd * g2[d0 + 1] + b2[d0 + 1];
    pln[d0 + 2] = (v.z - mean) * rstd * g2[d0 + 2] + b2[d0 + 2];
    pln[d0 + 3] = (v.w - mean) * rstd * g2[d0 + 3] + b2[d0 + 3];
    __syncthreads();
    int q = tid & 15, c = tid >> 4;
    if (c < 14) {
        float s = 0.f;
#pragma unroll 8
        for (int i = 0; i < 64; ++i) {
            int d = i * 16 + q;
            s += pln[d] * Wp[c * DD + d];
        }
#pragma unroll
        for (int m = 1; m < 16; m <<= 1) s += __shfl_xor(s, m, 64);
        if (q == 0) out[b * 14 + c] = s + bp[c];
    }
}

extern "C" void kernel_launch(void* const* d_in, const int* in_sizes, int n_in,
                              void* d_out, int out_size, void* d_ws, size_t ws_size,
                              hipStream_t stream) {
    const float* cls   = (const float*)d_in[0];
    const float* sto   = (const float*)d_in[1];
    const float* pat   = (const float*)d_in[2];
    const float* query = (const float*)d_in[3];
    const float* g     = (const float*)d_in[4];
    const float* bln   = (const float*)d_in[5];
    const float* Wq    = (const float*)d_in[6];
    const float* Wk    = (const float*)d_in[7];
    const float* Wv    = (const float*)d_in[8];
    const float* bq    = (const float*)d_in[9];
    const float* bk    = (const float*)d_in[10];
    const float* bv    = (const float*)d_in[11];
    const float* Wo    = (const float*)d_in[12];
    const float* bo    = (const float*)d_in[13];
    const float* g2    = (const float*)d_in[14];
    const float* b2    = (const float*)d_in[15];
    const float* Wp    = (const float*)d_in[16];
    const float* bp    = (const float*)d_in[17];

    float* ws     = (float*)d_ws;
    float* qvec   = ws + WS_QVEC;
    float* gu     = ws + WS_GU;
    float* Gv     = ws + WS_G;
    float* Bu     = ws + WS_BU;
    float* CB     = ws + WS_CB;
    float* pl     = ws + WS_PL;
    float* pM     = ws + WS_PM;
    float* pA     = ws + WS_PA;
    float* ctx    = ws + WS_CTX;
    float* pooled = ws + WS_POOL;
    float* out    = (float*)d_out;

    hipLaunchKernelGGL(k_qvec, dim3(1024), dim3(64), 0, stream, query, Wq, bq, qvec);
    hipLaunchKernelGGL(k_u,    dim3(16),   dim3(256), 0, stream, Wk, qvec, g, bln, gu, Gv, Bu);
    hipLaunchKernelGGL(k_cq,   dim3(1),    dim3(64), 0, stream, qvec, bk, Bu, CB);
    hipLaunchKernelGGL(k_main, dim3(BB * NCH), dim3(256), 0, stream,
                       cls, sto, pat, gu, Gv, CB, pA, pl, pM);
    hipLaunchKernelGGL(k_comb, dim3(BB * HH), dim3(256), 0, stream, pA, pl, pM, g, bln);
    hipLaunchKernelGGL(k_ctx,  dim3(1024), dim3(256), 0, stream, Wv, bv, pA, ctx);
    hipLaunchKernelGGL(k_pool, dim3(1024), dim3(256), 0, stream, Wo, bo, ctx, pooled);
    hipLaunchKernelGGL(k_head, dim3(64),   dim3(256), 0, stream, pooled, g2, b2, Wp, bp, out);
}